// Round 1
// baseline (880.671 us; speedup 1.0000x reference)
//
#include <hip/hip_runtime.h>
#include <math.h>

#define BB 64
#define SS 21
#define NSAMP 3000
#define HID 500
#define SECN 6
#define NN 2
#define ATT 128
#define OUTD 128
#define NPROTO 25
#define NCLS 5
#define NHEAD 4
#define BS (BB*SS)          // 1344
#define NSAMPLE (BS*NN)     // 2688

// ---------------- Kernel 1: hard attention -> section index ----------------
__global__ __launch_bounds__(256) void attn_kernel(
    const float* __restrict__ x, const float* __restrict__ gumbel,
    const float* __restrict__ wq, const float* __restrict__ wk,
    int* __restrict__ sec_idx) {
  __shared__ float xp[SECN * HID];      // 3000
  __shared__ float red[SECN * 256];     // 1536
  __shared__ float logits_sh[NN * SECN];
  const int b = blockIdx.x;
  const int t = threadIdx.x;

  // load x row + positional encoding (d = HID = 500)
  for (int idx = t; idx < SECN * HID; idx += 256) {
    int s = idx / HID, h = idx % HID;
    int i = h >> 1;
    float div = expf((float)(2 * i) * -0.0184206807439523674f); // -ln(1e4)/500
    float ang = (float)s * div;
    float pe = (h & 1) ? cosf(ang) : sinf(ang);
    xp[idx] = x[b * NSAMP + idx] + pe;
  }
  __syncthreads();

  // thread t owns column t of q and k (col = n*128 + h_att, n = t>>7)
  float qa[SECN], ka[SECN];
#pragma unroll
  for (int s = 0; s < SECN; s++) { qa[s] = 0.f; ka[s] = 0.f; }
  for (int h = 0; h < HID; h++) {
    float wqv = wq[h * 256 + t];
    float wkv = wk[h * 256 + t];
#pragma unroll
    for (int s = 0; s < SECN; s++) {
      float xv = xp[s * HID + h];
      qa[s] += xv * wqv;
      ka[s] += xv * wkv;
    }
  }
  float ksum = 0.f;
#pragma unroll
  for (int s = 0; s < SECN; s++) ksum += ka[s];
#pragma unroll
  for (int s = 0; s < SECN; s++) red[s * 256 + t] = qa[s] * ksum;
  __syncthreads();

  // logits[n][s] = sum over the 128 columns of half n, scaled
  if (t < NN * SECN) {
    int n = t / SECN, s = t % SECN;
    float acc = 0.f;
    const float* r = &red[s * 256 + n * 128];
    for (int j = 0; j < 128; j++) acc += r[j];
    // 1/(6*sqrt(500))
    float logit = acc * 0.00745355992499929898f;
    logits_sh[n * SECN + s] = logit + gumbel[(b * NN + n) * SECN + s];
  }
  __syncthreads();
  if (t < NN) {
    const float* l = &logits_sh[t * SECN];
    int best = 0; float bv = l[0];
    for (int s = 1; s < SECN; s++) { float v = l[s]; if (v > bv) { bv = v; best = s; } }
    sec_idx[b * NN + t] = best;
  }
}

// ---------------- Kernel 2: conv encoder + prototype argmin ----------------
__global__ __launch_bounds__(256) void conv_kernel(
    const float* __restrict__ x, const int* __restrict__ sec_idx,
    const float* __restrict__ w1, const float* __restrict__ b1,
    const float* __restrict__ bn1g, const float* __restrict__ bn1b,
    const float* __restrict__ w2, const float* __restrict__ b2,
    const float* __restrict__ bn2g, const float* __restrict__ bn2b,
    const float* __restrict__ w3, const float* __restrict__ b3,
    const float* __restrict__ bn3g, const float* __restrict__ bn3b,
    const float* __restrict__ fcw, const float* __restrict__ fcb,
    const float* __restrict__ fc2w, const float* __restrict__ fc2b,
    const float* __restrict__ protos, int* __restrict__ proto_idx) {
  __shared__ float in0[HID];        // 500
  __shared__ float buf1[32 * 125];  // 4000
  __shared__ float w2s[64 * 32 * 3];// 6144
  __shared__ float buf2[64 * 25];   // 1600
  __shared__ float buf3[128 * 6];   // 768
  __shared__ float fco[256];
  __shared__ float zsh[128];
  __shared__ float d2[NPROTO];

  const int sample = blockIdx.x;
  const int t = threadIdx.x;
  const int bsIdx = sample >> 1;
  const float bnscale = rsqrtf(1.0f + 1e-5f);

  {
    int sec = sec_idx[sample];
    const float* src = &x[bsIdx * NSAMP + sec * HID];
    for (int h = t; h < HID; h += 256) in0[h] = src[h];
    for (int i = t; i < 64 * 32 * 3; i += 256) w2s[i] = w2[i];
  }
  __syncthreads();

  // conv1 (1->32, k3 pad1) + relu + pool4 + bn : out 32 x 125
  for (int o = t; o < 32 * 125; o += 256) {
    int c = o / 125, p = o % 125;
    int base = 4 * p;
    float w0 = w1[c * 3], wv1 = w1[c * 3 + 1], wv2 = w1[c * 3 + 2], bb = b1[c];
    const float* ip = &in0[base];
    float xm1 = (base >= 1) ? ip[-1] : 0.f;
    float x0 = ip[0], x1 = ip[1], x2 = ip[2], x3 = ip[3];
    float x4 = (base + 4 < HID) ? ip[4] : 0.f;
    float a0 = bb + w0 * xm1 + wv1 * x0 + wv2 * x1;
    float a1 = bb + w0 * x0  + wv1 * x1 + wv2 * x2;
    float a2 = bb + w0 * x1  + wv1 * x2 + wv2 * x3;
    float a3 = bb + w0 * x2  + wv1 * x3 + wv2 * x4;
    float m = fmaxf(fmaxf(fmaxf(fmaxf(a0, a1), a2), a3), 0.f);
    buf1[o] = m * (bn1g[c] * bnscale) + bn1b[c];
  }
  __syncthreads();

  // conv2 (32->64, k3 pad1) + relu + pool5 + bn : out 64 x 25
  for (int o = t; o < 64 * 25; o += 256) {
    int c = o / 25, p = o % 25;
    int base = 5 * p;
    float bb = b2[c];
    float a0 = bb, a1 = bb, a2 = bb, a3 = bb, a4 = bb;
    const float* wrow = &w2s[c * 96];
    for (int ic = 0; ic < 32; ic++) {
      float w0 = wrow[ic * 3], wv1 = wrow[ic * 3 + 1], wv2 = wrow[ic * 3 + 2];
      const float* ip = &buf1[ic * 125 + base];
      float xm1 = (base >= 1) ? ip[-1] : 0.f;
      float x0 = ip[0], x1 = ip[1], x2 = ip[2], x3 = ip[3], x4 = ip[4];
      float x5 = (base + 5 < 125) ? ip[5] : 0.f;
      a0 += w0 * xm1 + wv1 * x0 + wv2 * x1;
      a1 += w0 * x0  + wv1 * x1 + wv2 * x2;
      a2 += w0 * x1  + wv1 * x2 + wv2 * x3;
      a3 += w0 * x2  + wv1 * x3 + wv2 * x4;
      a4 += w0 * x3  + wv1 * x4 + wv2 * x5;
    }
    float m = fmaxf(fmaxf(fmaxf(fmaxf(fmaxf(a0, a1), a2), a3), a4), 0.f);
    buf2[o] = m * (bn2g[c] * bnscale) + bn2b[c];
  }
  __syncthreads();

  // conv3 (64->128, k3 pad1) + relu + pool4(floor: first 24) + bn : out 128 x 6
  for (int o = t; o < 128 * 6; o += 256) {
    int c = o / 6, p = o % 6;
    int base = 4 * p;   // 0..20, window needs in[base-1 .. base+4], base+4<=24 ok
    float bb = b3[c];
    float a0 = bb, a1 = bb, a2 = bb, a3 = bb;
    for (int ic = 0; ic < 64; ic++) {
      const float* wp = &w3[(c * 64 + ic) * 3];
      float w0 = wp[0], wv1 = wp[1], wv2 = wp[2];
      const float* ip = &buf2[ic * 25 + base];
      float xm1 = (base >= 1) ? ip[-1] : 0.f;
      float x0 = ip[0], x1 = ip[1], x2 = ip[2], x3 = ip[3], x4 = ip[4];
      a0 += w0 * xm1 + wv1 * x0 + wv2 * x1;
      a1 += w0 * x0  + wv1 * x1 + wv2 * x2;
      a2 += w0 * x1  + wv1 * x2 + wv2 * x3;
      a3 += w0 * x2  + wv1 * x3 + wv2 * x4;
    }
    float m = fmaxf(fmaxf(fmaxf(fmaxf(a0, a1), a2), a3), 0.f);
    buf3[o] = m * (bn3g[c] * bnscale) + bn3b[c];
  }
  __syncthreads();

  // fc: 768 -> 256
  {
    float a = fcb[t];
    for (int i = 0; i < 768; i++) a += buf3[i] * fcw[i * 256 + t];
    fco[t] = a;
  }
  __syncthreads();
  // fc2: 256 -> 128
  if (t < 128) {
    float a = fc2b[t];
    for (int i = 0; i < 256; i++) a += fco[i] * fc2w[i * 128 + t];
    zsh[t] = a;
  }
  __syncthreads();
  // prototype argmin: d2 ~ |p|^2 - 2 z.p  (|z|^2 constant wrt argmin)
  if (t < NPROTO) {
    float acc = 0.f;
    const float* pp = &protos[t * OUTD];
    for (int i = 0; i < OUTD; i++) { float pv = pp[i]; acc += pv * pv - 2.f * pv * zsh[i]; }
    d2[t] = acc;
  }
  __syncthreads();
  if (t == 0) {
    int best = 0; float bv = d2[0];
    for (int i = 1; i < NPROTO; i++) { float v = d2[i]; if (v < bv) { bv = v; best = i; } }
    proto_idx[sample] = best;
  }
}

// ---------------- Kernel 3: sequence transformer + classifier ----------------
__global__ __launch_bounds__(256) void seq_kernel(
    const int* __restrict__ proto_idx, const float* __restrict__ protos,
    const float* __restrict__ inw, const float* __restrict__ inb,
    const float* __restrict__ outw, const float* __restrict__ outb,
    const float* __restrict__ ln1g, const float* __restrict__ ln1b,
    const float* __restrict__ ln2g, const float* __restrict__ ln2b,
    const float* __restrict__ ff1w, const float* __restrict__ ff1b,
    const float* __restrict__ ff2w, const float* __restrict__ ff2b,
    const float* __restrict__ clfw, const float* __restrict__ clfb,
    float* __restrict__ out) {
  __shared__ float hsh[SS * OUTD];      // 2688
  __shared__ float big[SS * 3 * OUTD];  // 8064  (qkv, later reused as tmp)
  __shared__ float sc[NHEAD * SS * SS]; // 1764
  __shared__ float ctx[SS * OUTD];      // 2688
  __shared__ float rowm[SS], rowv[SS];

  const int b = blockIdx.x;
  const int t = threadIdx.x;

  // h = mean of the two selected protos + PE(d=128)
  for (int o = t; o < SS * OUTD; o += 256) {
    int s = o >> 7, d = o & 127;
    int i0 = proto_idx[(b * SS + s) * 2];
    int i1 = proto_idx[(b * SS + s) * 2 + 1];
    float pc = 0.5f * (protos[i0 * OUTD + d] + protos[i1 * OUTD + d]);
    int i = d >> 1;
    float div = expf((float)(2 * i) * -0.07195578415606439f); // -ln(1e4)/128
    float ang = (float)s * div;
    float pe = (d & 1) ? cosf(ang) : sinf(ang);
    hsh[o] = pc + pe;
  }
  __syncthreads();

  // qkv = h @ in_w + in_b  : 21 x 384
  for (int o = t; o < SS * 384; o += 256) {
    int s = o / 384, j = o % 384;
    float a = inb[j];
    const float* hr = &hsh[s * OUTD];
    for (int d = 0; d < OUTD; d++) a += hr[d] * inw[d * 384 + j];
    big[o] = a;
  }
  __syncthreads();

  // scores per head
  for (int o = t; o < NHEAD * SS * SS; o += 256) {
    int hd = o / (SS * SS), r = o % (SS * SS), qs = r / SS, ks = r % SS;
    const float* qp = &big[qs * 384 + hd * 32];
    const float* kp = &big[ks * 384 + 128 + hd * 32];
    float a = 0.f;
    for (int d = 0; d < 32; d++) a += qp[d] * kp[d];
    sc[o] = a * 0.17677669529663689f; // 1/sqrt(32)
  }
  __syncthreads();
  // softmax over last axis, 84 rows
  for (int r = t; r < NHEAD * SS; r += 256) {
    float* row = &sc[r * SS];
    float mx = row[0];
    for (int i = 1; i < SS; i++) mx = fmaxf(mx, row[i]);
    float sum = 0.f;
    for (int i = 0; i < SS; i++) { float e = expf(row[i] - mx); row[i] = e; sum += e; }
    float inv = 1.f / sum;
    for (int i = 0; i < SS; i++) row[i] *= inv;
  }
  __syncthreads();
  // ctx
  for (int o = t; o < SS * OUTD; o += 256) {
    int qs = o >> 7, d = o & 127, hd = d >> 5, dd = d & 31;
    const float* srow = &sc[(hd * SS + qs) * SS];
    float a = 0.f;
    for (int ks = 0; ks < SS; ks++) a += srow[ks] * big[ks * 384 + 256 + hd * 32 + dd];
    ctx[o] = a;
  }
  __syncthreads();
  // attn out + residual -> tmp (reuse big)
  float* tmp = big;
  for (int o = t; o < SS * OUTD; o += 256) {
    int s = o >> 7, d = o & 127;
    float a = outb[d];
    const float* cr = &ctx[s * OUTD];
    for (int e = 0; e < OUTD; e++) a += cr[e] * outw[e * OUTD + d];
    tmp[o] = hsh[o] + a;
  }
  __syncthreads();
  // LN1
  if (t < SS) {
    const float* r = &tmp[t * OUTD];
    float m = 0.f;
    for (int d = 0; d < OUTD; d++) m += r[d];
    m *= (1.0f / OUTD);
    float v = 0.f;
    for (int d = 0; d < OUTD; d++) { float u = r[d] - m; v += u * u; }
    v *= (1.0f / OUTD);
    rowm[t] = m; rowv[t] = rsqrtf(v + 1e-5f);
  }
  __syncthreads();
  for (int o = t; o < SS * OUTD; o += 256) {
    int s = o >> 7, d = o & 127;
    hsh[o] = (tmp[o] - rowm[s]) * rowv[s] * ln1g[d] + ln1b[d];
  }
  __syncthreads();
  // ff1 -> ctx (relu)
  for (int o = t; o < SS * OUTD; o += 256) {
    int s = o >> 7, d = o & 127;
    float a = ff1b[d];
    const float* hr = &hsh[s * OUTD];
    for (int e = 0; e < OUTD; e++) a += hr[e] * ff1w[e * OUTD + d];
    ctx[o] = fmaxf(a, 0.f);
  }
  __syncthreads();
  // ff2 + residual -> tmp
  for (int o = t; o < SS * OUTD; o += 256) {
    int s = o >> 7, d = o & 127;
    float a = ff2b[d];
    const float* cr = &ctx[s * OUTD];
    for (int e = 0; e < OUTD; e++) a += cr[e] * ff2w[e * OUTD + d];
    tmp[o] = hsh[o] + a;
  }
  __syncthreads();
  // LN2
  if (t < SS) {
    const float* r = &tmp[t * OUTD];
    float m = 0.f;
    for (int d = 0; d < OUTD; d++) m += r[d];
    m *= (1.0f / OUTD);
    float v = 0.f;
    for (int d = 0; d < OUTD; d++) { float u = r[d] - m; v += u * u; }
    v *= (1.0f / OUTD);
    rowm[t] = m; rowv[t] = rsqrtf(v + 1e-5f);
  }
  __syncthreads();
  for (int o = t; o < SS * OUTD; o += 256) {
    int s = o >> 7, d = o & 127;
    hsh[o] = (tmp[o] - rowm[s]) * rowv[s] * ln2g[d] + ln2b[d];
  }
  __syncthreads();
  // classifier 128 -> 5
  for (int o = t; o < SS * NCLS; o += 256) {
    int s = o / NCLS, c = o % NCLS;
    float a = clfb[c];
    const float* hr = &hsh[s * OUTD];
    for (int d = 0; d < OUTD; d++) a += hr[d] * clfw[d * NCLS + c];
    out[(b * SS + s) * NCLS + c] = a;
  }
}

extern "C" void kernel_launch(void* const* d_in, const int* in_sizes, int n_in,
                              void* d_out, int out_size, void* d_ws, size_t ws_size,
                              hipStream_t stream) {
  const float* x     = (const float*)d_in[0];
  const float* gum   = (const float*)d_in[1];
  const float* wq    = (const float*)d_in[2];
  const float* wk    = (const float*)d_in[3];
  const float* w1    = (const float*)d_in[4];
  const float* b1    = (const float*)d_in[5];
  const float* bn1g  = (const float*)d_in[6];
  const float* bn1b  = (const float*)d_in[7];
  const float* w2    = (const float*)d_in[8];
  const float* b2    = (const float*)d_in[9];
  const float* bn2g  = (const float*)d_in[10];
  const float* bn2b  = (const float*)d_in[11];
  const float* w3    = (const float*)d_in[12];
  const float* b3    = (const float*)d_in[13];
  const float* bn3g  = (const float*)d_in[14];
  const float* bn3b  = (const float*)d_in[15];
  const float* fcw   = (const float*)d_in[16];
  const float* fcb   = (const float*)d_in[17];
  const float* fc2w  = (const float*)d_in[18];
  const float* fc2b  = (const float*)d_in[19];
  const float* prot  = (const float*)d_in[20];
  const float* inw   = (const float*)d_in[21];
  const float* inb   = (const float*)d_in[22];
  const float* outw  = (const float*)d_in[23];
  const float* outb  = (const float*)d_in[24];
  const float* ln1g  = (const float*)d_in[25];
  const float* ln1b  = (const float*)d_in[26];
  const float* ln2g  = (const float*)d_in[27];
  const float* ln2b  = (const float*)d_in[28];
  const float* ff1w  = (const float*)d_in[29];
  const float* ff1b  = (const float*)d_in[30];
  const float* ff2w  = (const float*)d_in[31];
  const float* ff2b  = (const float*)d_in[32];
  const float* clfw  = (const float*)d_in[33];
  const float* clfb  = (const float*)d_in[34];
  float* out = (float*)d_out;

  int* sec_idx   = (int*)d_ws;
  int* proto_idx = sec_idx + NSAMPLE;

  hipLaunchKernelGGL(attn_kernel, dim3(BS), dim3(256), 0, stream,
                     x, gum, wq, wk, sec_idx);
  hipLaunchKernelGGL(conv_kernel, dim3(NSAMPLE), dim3(256), 0, stream,
                     x, sec_idx, w1, b1, bn1g, bn1b, w2, b2, bn2g, bn2b,
                     w3, b3, bn3g, bn3b, fcw, fcb, fc2w, fc2b, prot, proto_idx);
  hipLaunchKernelGGL(seq_kernel, dim3(BB), dim3(256), 0, stream,
                     proto_idx, prot, inw, inb, outw, outb,
                     ln1g, ln1b, ln2g, ln2b, ff1w, ff1b, ff2w, ff2b,
                     clfw, clfb, out);
}

// Round 2
// 430.865 us; speedup vs baseline: 2.0440x; 2.0440x over previous
//
#include <hip/hip_runtime.h>
#include <math.h>

#define BB 64
#define SS 21
#define NSAMP 3000
#define HID 500
#define SECN 6
#define NN 2
#define OUTD 128
#define NPROTO 25
#define NCLS 5
#define NHEAD 4
#define BS (BB*SS)          // 1344
#define NSAMPLE (BS*NN)     // 2688

#define ST1 36
#define R1  127
#define ST2 68
#define R2  27

// ws float offsets
#define WS_W2T 5376
#define WS_W3T (WS_W2T + 6144)
#define WS_FEAT (WS_W3T + 24576)
#define FCSAMP 16

__device__ __forceinline__ float dot4(float4 a, float4 b) {
  return a.x*b.x + a.y*b.y + a.z*b.z + a.w*b.w;
}

// ---------------- Kernel 0: weight transposes into ws ----------------
__global__ __launch_bounds__(256) void prep_kernel(
    const float* __restrict__ w2, const float* __restrict__ w3,
    float* __restrict__ w2t, float* __restrict__ w3t) {
  int idx = blockIdx.x * 256 + threadIdx.x;
  if (idx < 6144) {
    int ic = idx & 31, ck = idx >> 5, k = ck % 3, c = ck / 3;
    w2t[idx] = w2[c * 96 + ic * 3 + k];
  } else if (idx < 6144 + 24576) {
    int j = idx - 6144;
    int ic = j & 63, ck = j >> 6, k = ck % 3, c = ck / 3;
    w3t[j] = w3[(c * 64 + ic) * 3 + k];
  }
}

// ---------------- Kernel 1: hard attention -> section index ----------------
// Algebraic form: logit[n,s] = xp[s] . (wq_n @ (xsum @ wk_n)) * scale + gumbel
// 4 samples/block, 512 threads.
__global__ __launch_bounds__(512, 4) void attn_kernel(
    const float* __restrict__ x, const float* __restrict__ gumbel,
    const float* __restrict__ wq, const float* __restrict__ wk,
    int* __restrict__ sec_idx) {
  __shared__ __align__(16) float xp[4 * SECN * HID];   // 48000 B
  __shared__ __align__(16) float xsum[4 * HID];        // 8000 B
  __shared__ __align__(16) float ks[4 * 256];          // 4096 B
  __shared__ __align__(16) float vbuf[4 * 2 * HID];    // 16000 B (ks-partial alias, then v)
  __shared__ float lg[4][NN][SECN];
  const int blk = blockIdx.x;
  const int t = threadIdx.x;
  float4* xpf4 = reinterpret_cast<float4*>(xp);
  float4* xsf4 = reinterpret_cast<float4*>(xsum);
  float4* ksf4 = reinterpret_cast<float4*>(ks);
  float4* vf4  = reinterpret_cast<float4*>(vbuf);

  // phase 1: load x + positional encoding (500 = 125 float4 per section row)
  for (int e = t; e < 4 * SECN * 125; e += 512) {
    int smp = e / 750, rem = e % 750, s = rem / 125, h4 = rem % 125;
    float4 xv = reinterpret_cast<const float4*>(x)[(blk * 4 + smp) * 750 + rem];
    float4 o;
    float* ov = (float*)&o; const float* iv = (const float*)&xv;
#pragma unroll
    for (int j = 0; j < 4; j++) {
      int h = h4 * 4 + j;
      int i = h >> 1;
      float div = expf((float)(2 * i) * -0.0184206807439523674f); // -ln(1e4)/500
      float ang = (float)s * div;
      float pe = (h & 1) ? cosf(ang) : sinf(ang);
      ov[j] = iv[j] + pe;
    }
    xpf4[e] = o;
  }
  __syncthreads();

  // phase 1b: xsum[smp][h] = sum_s xp[smp][s][h]
  if (t < 500) {
    int smp = t / 125, h4 = t % 125;
    float4 a = xpf4[(smp * 6 + 0) * 125 + h4];
#pragma unroll
    for (int s = 1; s < SECN; s++) {
      float4 b = xpf4[(smp * 6 + s) * 125 + h4];
      a.x += b.x; a.y += b.y; a.z += b.z; a.w += b.w;
    }
    xsf4[smp * 125 + h4] = a;
  }
  __syncthreads();

  // phase 2: ks[smp][col] = sum_h xsum[smp][h] * wk[h][col]  (h split 2-way)
  {
    float* ksp = vbuf;   // [2][4][256] partials
    int col = t & 255, hh = t >> 8;
    int b4 = hh ? 62 : 0, e4 = hh ? 125 : 62;
    float4 acc0 = make_float4(0.f,0.f,0.f,0.f), acc1 = acc0, acc2 = acc0, acc3 = acc0;
    for (int h4 = b4; h4 < e4; h4++) {
      int h = h4 * 4;
      float w0 = wk[(h + 0) * 256 + col];
      float w1 = wk[(h + 1) * 256 + col];
      float w2 = wk[(h + 2) * 256 + col];
      float w3 = wk[(h + 3) * 256 + col];
      float4 xs0 = xsf4[0 * 125 + h4];
      float4 xs1 = xsf4[1 * 125 + h4];
      float4 xs2 = xsf4[2 * 125 + h4];
      float4 xs3 = xsf4[3 * 125 + h4];
      acc0.x += xs0.x * w0; acc0.y += xs0.y * w1; acc0.z += xs0.z * w2; acc0.w += xs0.w * w3;
      acc1.x += xs1.x * w0; acc1.y += xs1.y * w1; acc1.z += xs1.z * w2; acc1.w += xs1.w * w3;
      acc2.x += xs2.x * w0; acc2.y += xs2.y * w1; acc2.z += xs2.z * w2; acc2.w += xs2.w * w3;
      acc3.x += xs3.x * w0; acc3.y += xs3.y * w1; acc3.z += xs3.z * w2; acc3.w += xs3.w * w3;
    }
    ksp[hh * 1024 + 0 * 256 + col] = (acc0.x + acc0.y) + (acc0.z + acc0.w);
    ksp[hh * 1024 + 1 * 256 + col] = (acc1.x + acc1.y) + (acc1.z + acc1.w);
    ksp[hh * 1024 + 2 * 256 + col] = (acc2.x + acc2.y) + (acc2.z + acc2.w);
    ksp[hh * 1024 + 3 * 256 + col] = (acc3.x + acc3.y) + (acc3.z + acc3.w);
  }
  __syncthreads();
  for (int e = t; e < 1024; e += 512) ks[e] = vbuf[e] + vbuf[1024 + e];
  __syncthreads();

  // phase 3: v[smp][n][h] = sum_{col in head n} wq[h][col] * ks[smp][col]
  if (t < 500) {
    int h = t;
    const float4* wqr = reinterpret_cast<const float4*>(wq + h * 256);
    float4 accA0 = make_float4(0.f,0.f,0.f,0.f), accA1 = accA0, accA2 = accA0, accA3 = accA0;
    for (int c4 = 0; c4 < 32; c4++) {
      float4 wv = wqr[c4];
      float4 k0 = ksf4[0 * 64 + c4], k1 = ksf4[1 * 64 + c4];
      float4 k2 = ksf4[2 * 64 + c4], k3 = ksf4[3 * 64 + c4];
      accA0.x += wv.x*k0.x; accA0.y += wv.y*k0.y; accA0.z += wv.z*k0.z; accA0.w += wv.w*k0.w;
      accA1.x += wv.x*k1.x; accA1.y += wv.y*k1.y; accA1.z += wv.z*k1.z; accA1.w += wv.w*k1.w;
      accA2.x += wv.x*k2.x; accA2.y += wv.y*k2.y; accA2.z += wv.z*k2.z; accA2.w += wv.w*k2.w;
      accA3.x += wv.x*k3.x; accA3.y += wv.y*k3.y; accA3.z += wv.z*k3.z; accA3.w += wv.w*k3.w;
    }
    float4 accB0 = make_float4(0.f,0.f,0.f,0.f), accB1 = accB0, accB2 = accB0, accB3 = accB0;
    for (int c4 = 32; c4 < 64; c4++) {
      float4 wv = wqr[c4];
      float4 k0 = ksf4[0 * 64 + c4], k1 = ksf4[1 * 64 + c4];
      float4 k2 = ksf4[2 * 64 + c4], k3 = ksf4[3 * 64 + c4];
      accB0.x += wv.x*k0.x; accB0.y += wv.y*k0.y; accB0.z += wv.z*k0.z; accB0.w += wv.w*k0.w;
      accB1.x += wv.x*k1.x; accB1.y += wv.y*k1.y; accB1.z += wv.z*k1.z; accB1.w += wv.w*k1.w;
      accB2.x += wv.x*k2.x; accB2.y += wv.y*k2.y; accB2.z += wv.z*k2.z; accB2.w += wv.w*k2.w;
      accB3.x += wv.x*k3.x; accB3.y += wv.y*k3.y; accB3.z += wv.z*k3.z; accB3.w += wv.w*k3.w;
    }
    vbuf[(0 * 2 + 0) * 500 + h] = (accA0.x + accA0.y) + (accA0.z + accA0.w);
    vbuf[(1 * 2 + 0) * 500 + h] = (accA1.x + accA1.y) + (accA1.z + accA1.w);
    vbuf[(2 * 2 + 0) * 500 + h] = (accA2.x + accA2.y) + (accA2.z + accA2.w);
    vbuf[(3 * 2 + 0) * 500 + h] = (accA3.x + accA3.y) + (accA3.z + accA3.w);
    vbuf[(0 * 2 + 1) * 500 + h] = (accB0.x + accB0.y) + (accB0.z + accB0.w);
    vbuf[(1 * 2 + 1) * 500 + h] = (accB1.x + accB1.y) + (accB1.z + accB1.w);
    vbuf[(2 * 2 + 1) * 500 + h] = (accB2.x + accB2.y) + (accB2.z + accB2.w);
    vbuf[(3 * 2 + 1) * 500 + h] = (accB3.x + accB3.y) + (accB3.z + accB3.w);
  }
  __syncthreads();

  // phase 4: logits; 48 items x 8 lanes
  if (t < 384) {
    int item = t >> 3, part = t & 7;
    int smp = item / 12, n = (item % 12) / SECN, s = item % SECN;
    int beg = part * 16, end = beg + 16 > 125 ? 125 : beg + 16;
    const float4* xr = xpf4 + (smp * 6 + s) * 125;
    const float4* vr = vf4 + (smp * 2 + n) * 125;
    float4 a4 = make_float4(0.f,0.f,0.f,0.f);
    for (int h4 = beg; h4 < end; h4++) {
      float4 xv = xr[h4], vv = vr[h4];
      a4.x += xv.x * vv.x; a4.y += xv.y * vv.y; a4.z += xv.z * vv.z; a4.w += xv.w * vv.w;
    }
    float a = (a4.x + a4.y) + (a4.z + a4.w);
    a += __shfl_xor(a, 1);
    a += __shfl_xor(a, 2);
    a += __shfl_xor(a, 4);
    if (part == 0)
      lg[smp][n][s] = a * 0.00745355992499929898f
                    + gumbel[((blk * 4 + smp) * NN + n) * SECN + s];
  }
  __syncthreads();
  if (t < 8) {
    int smp = t >> 1, n = t & 1;
    const float* l = &lg[smp][n][0];
    int best = 0; float bv = l[0];
    for (int s = 1; s < SECN; s++) { float v = l[s]; if (v > bv) { bv = v; best = s; } }
    sec_idx[(blk * 4 + smp) * NN + n] = best;
  }
}

// ---------------- Kernel 2: conv encoder -> feat[sample][768] ----------------
__global__ __launch_bounds__(256, 4) void conv_kernel(
    const float* __restrict__ x, const int* __restrict__ sec_idx,
    const float* __restrict__ w1, const float* __restrict__ b1,
    const float* __restrict__ bn1g, const float* __restrict__ bn1b,
    const float* __restrict__ w2t, const float* __restrict__ b2,
    const float* __restrict__ bn2g, const float* __restrict__ bn2b,
    const float* __restrict__ w3t, const float* __restrict__ b3,
    const float* __restrict__ bn3g, const float* __restrict__ bn3b,
    float* __restrict__ feat) {
  __shared__ __align__(16) float in0[HID];
  __shared__ __align__(16) float buf1t[R1 * ST1];
  __shared__ __align__(16) float buf2t[R2 * ST2];

  const int sample = blockIdx.x;
  const int t = threadIdx.x;
  const int bsIdx = sample >> 1;
  const float bnscale = rsqrtf(1.0f + 1e-5f);

  {
    int sec = sec_idx[sample];
    const float* src = &x[bsIdx * NSAMP + sec * HID];
    for (int h = t; h < HID; h += 256) in0[h] = src[h];
    for (int i = t; i < ST1; i += 256) { buf1t[i] = 0.f; buf1t[126 * ST1 + i] = 0.f; }
    if (t < ST2) { buf2t[t] = 0.f; buf2t[26 * ST2 + t] = 0.f; }
  }
  __syncthreads();

  for (int o = t; o < 32 * 125; o += 256) {
    int c = o & 31, p = o >> 5;
    int base = 4 * p;
    float w0 = w1[c * 3], wv1 = w1[c * 3 + 1], wv2 = w1[c * 3 + 2], bb = b1[c];
    float xm1 = (base >= 1) ? in0[base - 1] : 0.f;
    float x0 = in0[base], x1 = in0[base + 1], x2 = in0[base + 2], x3 = in0[base + 3];
    float x4 = (base + 4 < HID) ? in0[base + 4] : 0.f;
    float a0 = bb + w0 * xm1 + wv1 * x0 + wv2 * x1;
    float a1 = bb + w0 * x0  + wv1 * x1 + wv2 * x2;
    float a2 = bb + w0 * x1  + wv1 * x2 + wv2 * x3;
    float a3 = bb + w0 * x2  + wv1 * x3 + wv2 * x4;
    float m = fmaxf(fmaxf(fmaxf(fmaxf(a0, a1), a2), a3), 0.f);
    buf1t[(p + 1) * ST1 + c] = m * (bn1g[c] * bnscale) + bn1b[c];
  }
  __syncthreads();

  for (int o = t; o < 400; o += 256) {
    int cq = o / 25, p = o % 25;
    int c0 = cq * 4;
    float acc[4][5];
#pragma unroll
    for (int ci = 0; ci < 4; ci++) {
      float bb = b2[c0 + ci];
#pragma unroll
      for (int j = 0; j < 5; j++) acc[ci][j] = bb;
    }
    for (int ic4 = 0; ic4 < 8; ic4++) {
      float4 in[7];
#pragma unroll
      for (int r = 0; r < 7; r++)
        in[r] = *reinterpret_cast<const float4*>(&buf1t[(5 * p + r) * ST1 + ic4 * 4]);
#pragma unroll
      for (int k = 0; k < 3; k++) {
        float4 w[4];
#pragma unroll
        for (int ci = 0; ci < 4; ci++)
          w[ci] = *reinterpret_cast<const float4*>(&w2t[((c0 + ci) * 3 + k) * 32 + ic4 * 4]);
#pragma unroll
        for (int ci = 0; ci < 4; ci++)
#pragma unroll
          for (int j = 0; j < 5; j++)
            acc[ci][j] += dot4(w[ci], in[j + k]);
      }
    }
#pragma unroll
    for (int ci = 0; ci < 4; ci++) {
      int c = c0 + ci;
      float m = fmaxf(fmaxf(fmaxf(fmaxf(fmaxf(acc[ci][0], acc[ci][1]), acc[ci][2]), acc[ci][3]), acc[ci][4]), 0.f);
      buf2t[(p + 1) * ST2 + c] = m * (bn2g[c] * bnscale) + bn2b[c];
    }
  }
  __syncthreads();

  if (t < 192) {
    int cq = t / 6, p = t % 6;
    int c0 = cq * 4;
    float acc[4][4];
#pragma unroll
    for (int ci = 0; ci < 4; ci++) {
      float bb = b3[c0 + ci];
#pragma unroll
      for (int j = 0; j < 4; j++) acc[ci][j] = bb;
    }
    for (int ic4 = 0; ic4 < 16; ic4++) {
      float4 in[6];
#pragma unroll
      for (int r = 0; r < 6; r++)
        in[r] = *reinterpret_cast<const float4*>(&buf2t[(4 * p + r) * ST2 + ic4 * 4]);
#pragma unroll
      for (int k = 0; k < 3; k++) {
        float4 w[4];
#pragma unroll
        for (int ci = 0; ci < 4; ci++)
          w[ci] = *reinterpret_cast<const float4*>(&w3t[((c0 + ci) * 3 + k) * 64 + ic4 * 4]);
#pragma unroll
        for (int ci = 0; ci < 4; ci++)
#pragma unroll
          for (int j = 0; j < 4; j++)
            acc[ci][j] += dot4(w[ci], in[j + k]);
      }
    }
#pragma unroll
    for (int ci = 0; ci < 4; ci++) {
      int c = c0 + ci;
      float m = fmaxf(fmaxf(fmaxf(fmaxf(acc[ci][0], acc[ci][1]), acc[ci][2]), acc[ci][3]), 0.f);
      feat[sample * 768 + c * 6 + p] = m * (bn3g[c] * bnscale) + bn3b[c];
    }
  }
}

// ---------------- Kernel 2b: fc GEMM (16 samples/block) + fc2 + proto argmin ----------------
__global__ __launch_bounds__(256, 2) void fc_kernel(
    const float* __restrict__ feat,
    const float* __restrict__ fcw, const float* __restrict__ fcb,
    const float* __restrict__ fc2w, const float* __restrict__ fc2b,
    const float* __restrict__ protos, int* __restrict__ proto_idx) {
  __shared__ __align__(16) float a_sh[FCSAMP * 768];
  __shared__ __align__(16) float fco[FCSAMP * 256];
  __shared__ __align__(16) float zsh[FCSAMP * 128];
  __shared__ float d2[FCSAMP][NPROTO];

  const int blk = blockIdx.x;
  const int t = threadIdx.x;
  const int s0 = blk * FCSAMP;

  for (int e = t; e < FCSAMP * 192; e += 256) {
    reinterpret_cast<float4*>(a_sh)[e] =
        reinterpret_cast<const float4*>(feat)[s0 * 192 + e];
  }
  __syncthreads();

  {
    float acc[FCSAMP];
    float bb = fcb[t];
#pragma unroll
    for (int m = 0; m < FCSAMP; m++) acc[m] = bb;
    for (int i = 0; i < 768; i++) {
      float wv = fcw[i * 256 + t];
#pragma unroll
      for (int m = 0; m < FCSAMP; m++)
        acc[m] += a_sh[m * 768 + i] * wv;
    }
#pragma unroll
    for (int m = 0; m < FCSAMP; m++) fco[m * 256 + t] = acc[m];
  }
  __syncthreads();

  if (t < 128) {
    float acc[FCSAMP];
    float bb = fc2b[t];
#pragma unroll
    for (int m = 0; m < FCSAMP; m++) acc[m] = bb;
    for (int i = 0; i < 256; i++) {
      float wv = fc2w[i * 128 + t];
#pragma unroll
      for (int m = 0; m < FCSAMP; m++)
        acc[m] += fco[m * 256 + i] * wv;
    }
#pragma unroll
    for (int m = 0; m < FCSAMP; m++) zsh[m * 128 + t] = acc[m];
  }
  __syncthreads();

  for (int o = t; o < FCSAMP * NPROTO; o += 256) {
    int m = o / NPROTO, pi = o % NPROTO;
    const float4* pp = reinterpret_cast<const float4*>(protos + pi * OUTD);
    const float4* zz = reinterpret_cast<const float4*>(zsh + m * OUTD);
    float acc = 0.f;
    for (int i4 = 0; i4 < 32; i4++) {
      float4 p4 = pp[i4], z4 = zz[i4];
      acc += p4.x * (p4.x - 2.f * z4.x) + p4.y * (p4.y - 2.f * z4.y)
           + p4.z * (p4.z - 2.f * z4.z) + p4.w * (p4.w - 2.f * z4.w);
    }
    d2[m][pi] = acc;
  }
  __syncthreads();
  if (t < FCSAMP) {
    int best = 0; float bv = d2[t][0];
    for (int i = 1; i < NPROTO; i++) { float v = d2[t][i]; if (v < bv) { bv = v; best = i; } }
    proto_idx[s0 + t] = best;
  }
}

// ---------------- Kernel 3: sequence transformer + classifier ----------------
__global__ __launch_bounds__(512) void seq_kernel(
    const int* __restrict__ proto_idx, const float* __restrict__ protos,
    const float* __restrict__ inw, const float* __restrict__ inb,
    const float* __restrict__ outw, const float* __restrict__ outb,
    const float* __restrict__ ln1g, const float* __restrict__ ln1b,
    const float* __restrict__ ln2g, const float* __restrict__ ln2b,
    const float* __restrict__ ff1w, const float* __restrict__ ff1b,
    const float* __restrict__ ff2w, const float* __restrict__ ff2b,
    const float* __restrict__ clfw, const float* __restrict__ clfb,
    float* __restrict__ out) {
  __shared__ __align__(16) float hsh[SS * OUTD];
  __shared__ __align__(16) float big[SS * 3 * OUTD];
  __shared__ __align__(16) float sc[NHEAD * SS * SS];
  __shared__ __align__(16) float ctx[SS * OUTD];
  __shared__ float rowm[SS], rowv[SS];

  const int b = blockIdx.x;
  const int t = threadIdx.x;

  for (int o = t; o < SS * OUTD; o += 512) {
    int s = o >> 7, d = o & 127;
    int i0 = proto_idx[(b * SS + s) * 2];
    int i1 = proto_idx[(b * SS + s) * 2 + 1];
    float pc = 0.5f * (protos[i0 * OUTD + d] + protos[i1 * OUTD + d]);
    int i = d >> 1;
    float div = expf((float)(2 * i) * -0.07195578415606439f);
    float ang = (float)s * div;
    float pe = (d & 1) ? cosf(ang) : sinf(ang);
    hsh[o] = pc + pe;
  }
  __syncthreads();

  for (int o = t; o < SS * 384; o += 512) {
    int s = o / 384, j = o % 384;
    float4 a4 = make_float4(0.f, 0.f, 0.f, 0.f);
    const float4* hr = reinterpret_cast<const float4*>(&hsh[s * OUTD]);
    for (int d4 = 0; d4 < 32; d4++) {
      float4 h4 = hr[d4];
      int d = d4 * 4;
      a4.x += h4.x * inw[(d + 0) * 384 + j];
      a4.y += h4.y * inw[(d + 1) * 384 + j];
      a4.z += h4.z * inw[(d + 2) * 384 + j];
      a4.w += h4.w * inw[(d + 3) * 384 + j];
    }
    big[o] = inb[j] + ((a4.x + a4.y) + (a4.z + a4.w));
  }
  __syncthreads();

  for (int o = t; o < NHEAD * SS * SS; o += 512) {
    int hd = o / (SS * SS), r = o % (SS * SS), qs = r / SS, ks = r % SS;
    const float4* qp = reinterpret_cast<const float4*>(&big[qs * 384 + hd * 32]);
    const float4* kp = reinterpret_cast<const float4*>(&big[ks * 384 + 128 + hd * 32]);
    float4 a4 = make_float4(0.f, 0.f, 0.f, 0.f);
#pragma unroll
    for (int d4 = 0; d4 < 8; d4++) {
      float4 q4 = qp[d4], k4 = kp[d4];
      a4.x += q4.x * k4.x; a4.y += q4.y * k4.y; a4.z += q4.z * k4.z; a4.w += q4.w * k4.w;
    }
    sc[o] = ((a4.x + a4.y) + (a4.z + a4.w)) * 0.17677669529663689f;
  }
  __syncthreads();
  for (int r = t; r < NHEAD * SS; r += 512) {
    float* row = &sc[r * SS];
    float mx = row[0];
    for (int i = 1; i < SS; i++) mx = fmaxf(mx, row[i]);
    float sum = 0.f;
    for (int i = 0; i < SS; i++) { float e = expf(row[i] - mx); row[i] = e; sum += e; }
    float inv = 1.f / sum;
    for (int i = 0; i < SS; i++) row[i] *= inv;
  }
  __syncthreads();
  for (int o = t; o < SS * OUTD; o += 512) {
    int qs = o >> 7, d = o & 127, hd = d >> 5, dd = d & 31;
    const float* srow = &sc[(hd * SS + qs) * SS];
    float a = 0.f;
    for (int ks = 0; ks < SS; ks++) a += srow[ks] * big[ks * 384 + 256 + hd * 32 + dd];
    ctx[o] = a;
  }
  __syncthreads();
  float* tmp = big;
  for (int o = t; o < SS * OUTD; o += 512) {
    int s = o >> 7, d = o & 127;
    float4 a4 = make_float4(0.f, 0.f, 0.f, 0.f);
    const float4* cr = reinterpret_cast<const float4*>(&ctx[s * OUTD]);
    for (int e4 = 0; e4 < 32; e4++) {
      float4 c4 = cr[e4];
      int e = e4 * 4;
      a4.x += c4.x * outw[(e + 0) * OUTD + d];
      a4.y += c4.y * outw[(e + 1) * OUTD + d];
      a4.z += c4.z * outw[(e + 2) * OUTD + d];
      a4.w += c4.w * outw[(e + 3) * OUTD + d];
    }
    tmp[o] = hsh[o] + outb[d] + ((a4.x + a4.y) + (a4.z + a4.w));
  }
  __syncthreads();
  if (t < SS) {
    const float4* r4 = reinterpret_cast<const float4*>(&tmp[t * OUTD]);
    float4 m4 = make_float4(0.f, 0.f, 0.f, 0.f);
    for (int d4 = 0; d4 < 32; d4++) {
      float4 v = r4[d4];
      m4.x += v.x; m4.y += v.y; m4.z += v.z; m4.w += v.w;
    }
    float m = ((m4.x + m4.y) + (m4.z + m4.w)) * (1.0f / OUTD);
    float4 v4 = make_float4(0.f, 0.f, 0.f, 0.f);
    for (int d4 = 0; d4 < 32; d4++) {
      float4 v = r4[d4];
      float ux = v.x - m, uy = v.y - m, uz = v.z - m, uw = v.w - m;
      v4.x += ux * ux; v4.y += uy * uy; v4.z += uz * uz; v4.w += uw * uw;
    }
    float var = ((v4.x + v4.y) + (v4.z + v4.w)) * (1.0f / OUTD);
    rowm[t] = m; rowv[t] = rsqrtf(var + 1e-5f);
  }
  __syncthreads();
  for (int o = t; o < SS * OUTD; o += 512) {
    int s = o >> 7, d = o & 127;
    hsh[o] = (tmp[o] - rowm[s]) * rowv[s] * ln1g[d] + ln1b[d];
  }
  __syncthreads();
  for (int o = t; o < SS * OUTD; o += 512) {
    int s = o >> 7, d = o & 127;
    float4 a4 = make_float4(0.f, 0.f, 0.f, 0.f);
    const float4* hr = reinterpret_cast<const float4*>(&hsh[s * OUTD]);
    for (int e4 = 0; e4 < 32; e4++) {
      float4 h4 = hr[e4];
      int e = e4 * 4;
      a4.x += h4.x * ff1w[(e + 0) * OUTD + d];
      a4.y += h4.y * ff1w[(e + 1) * OUTD + d];
      a4.z += h4.z * ff1w[(e + 2) * OUTD + d];
      a4.w += h4.w * ff1w[(e + 3) * OUTD + d];
    }
    ctx[o] = fmaxf(ff1b[d] + ((a4.x + a4.y) + (a4.z + a4.w)), 0.f);
  }
  __syncthreads();
  for (int o = t; o < SS * OUTD; o += 512) {
    int s = o >> 7, d = o & 127;
    float4 a4 = make_float4(0.f, 0.f, 0.f, 0.f);
    const float4* cr = reinterpret_cast<const float4*>(&ctx[s * OUTD]);
    for (int e4 = 0; e4 < 32; e4++) {
      float4 c4 = cr[e4];
      int e = e4 * 4;
      a4.x += c4.x * ff2w[(e + 0) * OUTD + d];
      a4.y += c4.y * ff2w[(e + 1) * OUTD + d];
      a4.z += c4.z * ff2w[(e + 2) * OUTD + d];
      a4.w += c4.w * ff2w[(e + 3) * OUTD + d];
    }
    tmp[o] = hsh[o] + ff2b[d] + ((a4.x + a4.y) + (a4.z + a4.w));
  }
  __syncthreads();
  if (t < SS) {
    const float4* r4 = reinterpret_cast<const float4*>(&tmp[t * OUTD]);
    float4 m4 = make_float4(0.f, 0.f, 0.f, 0.f);
    for (int d4 = 0; d4 < 32; d4++) {
      float4 v = r4[d4];
      m4.x += v.x; m4.y += v.y; m4.z += v.z; m4.w += v.w;
    }
    float m = ((m4.x + m4.y) + (m4.z + m4.w)) * (1.0f / OUTD);
    float4 v4 = make_float4(0.f, 0.f, 0.f, 0.f);
    for (int d4 = 0; d4 < 32; d4++) {
      float4 v = r4[d4];
      float ux = v.x - m, uy = v.y - m, uz = v.z - m, uw = v.w - m;
      v4.x += ux * ux; v4.y += uy * uy; v4.z += uz * uz; v4.w += uw * uw;
    }
    float var = ((v4.x + v4.y) + (v4.z + v4.w)) * (1.0f / OUTD);
    rowm[t] = m; rowv[t] = rsqrtf(var + 1e-5f);
  }
  __syncthreads();
  for (int o = t; o < SS * OUTD; o += 512) {
    int s = o >> 7, d = o & 127;
    hsh[o] = (tmp[o] - rowm[s]) * rowv[s] * ln2g[d] + ln2b[d];
  }
  __syncthreads();
  for (int o = t; o < SS * NCLS; o += 512) {
    int s = o / NCLS, c = o % NCLS;
    float4 a4 = make_float4(0.f, 0.f, 0.f, 0.f);
    const float4* hr = reinterpret_cast<const float4*>(&hsh[s * OUTD]);
    for (int d4 = 0; d4 < 32; d4++) {
      float4 h4 = hr[d4];
      int d = d4 * 4;
      a4.x += h4.x * clfw[(d + 0) * NCLS + c];
      a4.y += h4.y * clfw[(d + 1) * NCLS + c];
      a4.z += h4.z * clfw[(d + 2) * NCLS + c];
      a4.w += h4.w * clfw[(d + 3) * NCLS + c];
    }
    out[(b * SS + s) * NCLS + c] = clfb[c] + ((a4.x + a4.y) + (a4.z + a4.w));
  }
}

extern "C" void kernel_launch(void* const* d_in, const int* in_sizes, int n_in,
                              void* d_out, int out_size, void* d_ws, size_t ws_size,
                              hipStream_t stream) {
  const float* x     = (const float*)d_in[0];
  const float* gum   = (const float*)d_in[1];
  const float* wq    = (const float*)d_in[2];
  const float* wk    = (const float*)d_in[3];
  const float* w1    = (const float*)d_in[4];
  const float* b1    = (const float*)d_in[5];
  const float* bn1g  = (const float*)d_in[6];
  const float* bn1b  = (const float*)d_in[7];
  const float* w2    = (const float*)d_in[8];
  const float* b2    = (const float*)d_in[9];
  const float* bn2g  = (const float*)d_in[10];
  const float* bn2b  = (const float*)d_in[11];
  const float* w3    = (const float*)d_in[12];
  const float* b3    = (const float*)d_in[13];
  const float* bn3g  = (const float*)d_in[14];
  const float* bn3b  = (const float*)d_in[15];
  const float* fcw   = (const float*)d_in[16];
  const float* fcb   = (const float*)d_in[17];
  const float* fc2w  = (const float*)d_in[18];
  const float* fc2b  = (const float*)d_in[19];
  const float* prot  = (const float*)d_in[20];
  const float* inw   = (const float*)d_in[21];
  const float* inb   = (const float*)d_in[22];
  const float* outw  = (const float*)d_in[23];
  const float* outb  = (const float*)d_in[24];
  const float* ln1g  = (const float*)d_in[25];
  const float* ln1b  = (const float*)d_in[26];
  const float* ln2g  = (const float*)d_in[27];
  const float* ln2b  = (const float*)d_in[28];
  const float* ff1w  = (const float*)d_in[29];
  const float* ff1b  = (const float*)d_in[30];
  const float* ff2w  = (const float*)d_in[31];
  const float* ff2b  = (const float*)d_in[32];
  const float* clfw  = (const float*)d_in[33];
  const float* clfb  = (const float*)d_in[34];
  float* out = (float*)d_out;

  int* sec_idx   = (int*)d_ws;
  int* proto_idx = sec_idx + NSAMPLE;
  float* w2t  = (float*)d_ws + WS_W2T;
  float* w3t  = (float*)d_ws + WS_W3T;
  float* feat = (float*)d_ws + WS_FEAT;

  hipLaunchKernelGGL(prep_kernel, dim3(120), dim3(256), 0, stream, w2, w3, w2t, w3t);
  hipLaunchKernelGGL(attn_kernel, dim3(BS / 4), dim3(512), 0, stream,
                     x, gum, wq, wk, sec_idx);
  hipLaunchKernelGGL(conv_kernel, dim3(NSAMPLE), dim3(256), 0, stream,
                     x, sec_idx, w1, b1, bn1g, bn1b, w2t, b2, bn2g, bn2b,
                     w3t, b3, bn3g, bn3b, feat);
  hipLaunchKernelGGL(fc_kernel, dim3(NSAMPLE / FCSAMP), dim3(256), 0, stream,
                     feat, fcw, fcb, fc2w, fc2b, prot, proto_idx);
  hipLaunchKernelGGL(seq_kernel, dim3(BB), dim3(512), 0, stream,
                     proto_idx, prot, inw, inb, outw, outb,
                     ln1g, ln1b, ln2g, ln2b, ff1w, ff1b, ff2w, ff2b,
                     clfw, clfb, out);
}

// Round 3
// 294.332 us; speedup vs baseline: 2.9921x; 1.4639x over previous
//
#include <hip/hip_runtime.h>
#include <math.h>

#define BB 64
#define SS 21
#define NSAMP 3000
#define HID 500
#define SECN 6
#define NN 2
#define OUTD 128
#define NPROTO 25
#define NCLS 5
#define NHEAD 4
#define BS (BB*SS)          // 1344
#define NSAMPLE (BS*NN)     // 2688

// ws float offsets
#define WS_W2HI 5376
#define WS_W2LO 8448
#define WS_W3HI 11520
#define WS_W3LO 23808
#define WS_FEAT 36096
#define FCSAMP 16

typedef __attribute__((ext_vector_type(8))) short short8;
typedef __attribute__((ext_vector_type(4))) float floatx4;

__device__ __forceinline__ float dot4(float4 a, float4 b) {
  return a.x*b.x + a.y*b.y + a.z*b.z + a.w*b.w;
}
__device__ __forceinline__ short f2bf(float f) {
  unsigned u = __float_as_uint(f);
  u += 0x7FFF + ((u >> 16) & 1);          // RNE to bf16
  return (short)(u >> 16);
}
__device__ __forceinline__ float bf2f(short h) {
  return __uint_as_float(((unsigned)(unsigned short)h) << 16);
}

// ---------------- Kernel 0: weight hi/lo bf16 splits into ws ----------------
__global__ __launch_bounds__(256) void prep_kernel(
    const float* __restrict__ w2, const float* __restrict__ w3,
    short* __restrict__ w2hi, short* __restrict__ w2lo,
    short* __restrict__ w3hi, short* __restrict__ w3lo) {
  int idx = blockIdx.x * 256 + threadIdx.x;
  if (idx < 6144) {
    int ic = idx & 31, ck = idx >> 5, k = ck % 3, c = ck / 3;
    float v = w2[c * 96 + ic * 3 + k];
    int dst = c * 96 + k * 32 + ic;         // K = k*32+ic
    short hi = f2bf(v);
    short lo = f2bf(v - bf2f(hi));
    w2hi[dst] = hi; w2lo[dst] = lo;
  } else if (idx < 30720) {
    int j = idx - 6144;
    int ic = j & 63, ck = j >> 6, k = ck % 3, c = ck / 3;
    float v = w3[(c * 64 + ic) * 3 + k];
    int dst = c * 192 + k * 64 + ic;        // K = k*64+ic
    short hi = f2bf(v);
    short lo = f2bf(v - bf2f(hi));
    w3hi[dst] = hi; w3lo[dst] = lo;
  }
}

// ---------------- Kernel 1: hard attention -> section index ----------------
__global__ __launch_bounds__(512, 4) void attn_kernel(
    const float* __restrict__ x, const float* __restrict__ gumbel,
    const float* __restrict__ wq, const float* __restrict__ wk,
    int* __restrict__ sec_idx) {
  __shared__ __align__(16) float xp[4 * SECN * HID];
  __shared__ __align__(16) float xsum[4 * HID];
  __shared__ __align__(16) float ks[4 * 256];
  __shared__ __align__(16) float vbuf[4 * 2 * HID];
  __shared__ float lg[4][NN][SECN];
  const int blk = blockIdx.x;
  const int t = threadIdx.x;
  float4* xpf4 = reinterpret_cast<float4*>(xp);
  float4* xsf4 = reinterpret_cast<float4*>(xsum);
  float4* ksf4 = reinterpret_cast<float4*>(ks);
  float4* vf4  = reinterpret_cast<float4*>(vbuf);

  for (int e = t; e < 4 * SECN * 125; e += 512) {
    int rem = e % 750, s = rem / 125, h4 = rem % 125;
    float4 xv = reinterpret_cast<const float4*>(x)[blk * 3000 + e];
    float4 o;
    float* ov = (float*)&o; const float* iv = (const float*)&xv;
#pragma unroll
    for (int j = 0; j < 4; j++) {
      int h = h4 * 4 + j;
      int i = h >> 1;
      float div = expf((float)(2 * i) * -0.0184206807439523674f);
      float ang = (float)s * div;
      float pe = (h & 1) ? cosf(ang) : sinf(ang);
      ov[j] = iv[j] + pe;
    }
    xpf4[e] = o;
  }
  __syncthreads();

  if (t < 500) {
    int smp = t / 125, h4 = t % 125;
    float4 a = xpf4[(smp * 6 + 0) * 125 + h4];
#pragma unroll
    for (int s = 1; s < SECN; s++) {
      float4 b = xpf4[(smp * 6 + s) * 125 + h4];
      a.x += b.x; a.y += b.y; a.z += b.z; a.w += b.w;
    }
    xsf4[smp * 125 + h4] = a;
  }
  __syncthreads();

  {
    float* ksp = vbuf;
    int col = t & 255, hh = t >> 8;
    int b4 = hh ? 62 : 0, e4 = hh ? 125 : 62;
    float4 acc0 = make_float4(0.f,0.f,0.f,0.f), acc1 = acc0, acc2 = acc0, acc3 = acc0;
    for (int h4 = b4; h4 < e4; h4++) {
      int h = h4 * 4;
      float w0 = wk[(h + 0) * 256 + col];
      float w1 = wk[(h + 1) * 256 + col];
      float w2 = wk[(h + 2) * 256 + col];
      float w3 = wk[(h + 3) * 256 + col];
      float4 xs0 = xsf4[0 * 125 + h4];
      float4 xs1 = xsf4[1 * 125 + h4];
      float4 xs2 = xsf4[2 * 125 + h4];
      float4 xs3 = xsf4[3 * 125 + h4];
      acc0.x += xs0.x * w0; acc0.y += xs0.y * w1; acc0.z += xs0.z * w2; acc0.w += xs0.w * w3;
      acc1.x += xs1.x * w0; acc1.y += xs1.y * w1; acc1.z += xs1.z * w2; acc1.w += xs1.w * w3;
      acc2.x += xs2.x * w0; acc2.y += xs2.y * w1; acc2.z += xs2.z * w2; acc2.w += xs2.w * w3;
      acc3.x += xs3.x * w0; acc3.y += xs3.y * w1; acc3.z += xs3.z * w2; acc3.w += xs3.w * w3;
    }
    ksp[hh * 1024 + 0 * 256 + col] = (acc0.x + acc0.y) + (acc0.z + acc0.w);
    ksp[hh * 1024 + 1 * 256 + col] = (acc1.x + acc1.y) + (acc1.z + acc1.w);
    ksp[hh * 1024 + 2 * 256 + col] = (acc2.x + acc2.y) + (acc2.z + acc2.w);
    ksp[hh * 1024 + 3 * 256 + col] = (acc3.x + acc3.y) + (acc3.z + acc3.w);
  }
  __syncthreads();
  for (int e = t; e < 1024; e += 512) ks[e] = vbuf[e] + vbuf[1024 + e];
  __syncthreads();

  if (t < 500) {
    int h = t;
    const float4* wqr = reinterpret_cast<const float4*>(wq + h * 256);
    float4 accA0 = make_float4(0.f,0.f,0.f,0.f), accA1 = accA0, accA2 = accA0, accA3 = accA0;
    for (int c4 = 0; c4 < 32; c4++) {
      float4 wv = wqr[c4];
      float4 k0 = ksf4[0 * 64 + c4], k1 = ksf4[1 * 64 + c4];
      float4 k2 = ksf4[2 * 64 + c4], k3 = ksf4[3 * 64 + c4];
      accA0.x += wv.x*k0.x; accA0.y += wv.y*k0.y; accA0.z += wv.z*k0.z; accA0.w += wv.w*k0.w;
      accA1.x += wv.x*k1.x; accA1.y += wv.y*k1.y; accA1.z += wv.z*k1.z; accA1.w += wv.w*k1.w;
      accA2.x += wv.x*k2.x; accA2.y += wv.y*k2.y; accA2.z += wv.z*k2.z; accA2.w += wv.w*k2.w;
      accA3.x += wv.x*k3.x; accA3.y += wv.y*k3.y; accA3.z += wv.z*k3.z; accA3.w += wv.w*k3.w;
    }
    float4 accB0 = make_float4(0.f,0.f,0.f,0.f), accB1 = accB0, accB2 = accB0, accB3 = accB0;
    for (int c4 = 32; c4 < 64; c4++) {
      float4 wv = wqr[c4];
      float4 k0 = ksf4[0 * 64 + c4], k1 = ksf4[1 * 64 + c4];
      float4 k2 = ksf4[2 * 64 + c4], k3 = ksf4[3 * 64 + c4];
      accB0.x += wv.x*k0.x; accB0.y += wv.y*k0.y; accB0.z += wv.z*k0.z; accB0.w += wv.w*k0.w;
      accB1.x += wv.x*k1.x; accB1.y += wv.y*k1.y; accB1.z += wv.z*k1.z; accB1.w += wv.w*k1.w;
      accB2.x += wv.x*k2.x; accB2.y += wv.y*k2.y; accB2.z += wv.z*k2.z; accB2.w += wv.w*k2.w;
      accB3.x += wv.x*k3.x; accB3.y += wv.y*k3.y; accB3.z += wv.z*k3.z; accB3.w += wv.w*k3.w;
    }
    vbuf[(0 * 2 + 0) * 500 + h] = (accA0.x + accA0.y) + (accA0.z + accA0.w);
    vbuf[(1 * 2 + 0) * 500 + h] = (accA1.x + accA1.y) + (accA1.z + accA1.w);
    vbuf[(2 * 2 + 0) * 500 + h] = (accA2.x + accA2.y) + (accA2.z + accA2.w);
    vbuf[(3 * 2 + 0) * 500 + h] = (accA3.x + accA3.y) + (accA3.z + accA3.w);
    vbuf[(0 * 2 + 1) * 500 + h] = (accB0.x + accB0.y) + (accB0.z + accB0.w);
    vbuf[(1 * 2 + 1) * 500 + h] = (accB1.x + accB1.y) + (accB1.z + accB1.w);
    vbuf[(2 * 2 + 1) * 500 + h] = (accB2.x + accB2.y) + (accB2.z + accB2.w);
    vbuf[(3 * 2 + 1) * 500 + h] = (accB3.x + accB3.y) + (accB3.z + accB3.w);
  }
  __syncthreads();

  if (t < 384) {
    int item = t >> 3, part = t & 7;
    int smp = item / 12, n = (item % 12) / SECN, s = item % SECN;
    int beg = part * 16, end = beg + 16 > 125 ? 125 : beg + 16;
    const float4* xr = xpf4 + (smp * 6 + s) * 125;
    const float4* vr = vf4 + (smp * 2 + n) * 125;
    float4 a4 = make_float4(0.f,0.f,0.f,0.f);
    for (int h4 = beg; h4 < end; h4++) {
      float4 xv = xr[h4], vv = vr[h4];
      a4.x += xv.x * vv.x; a4.y += xv.y * vv.y; a4.z += xv.z * vv.z; a4.w += xv.w * vv.w;
    }
    float a = (a4.x + a4.y) + (a4.z + a4.w);
    a += __shfl_xor(a, 1);
    a += __shfl_xor(a, 2);
    a += __shfl_xor(a, 4);
    if (part == 0)
      lg[smp][n][s] = a * 0.00745355992499929898f
                    + gumbel[((blk * 4 + smp) * NN + n) * SECN + s];
  }
  __syncthreads();
  if (t < 8) {
    int smp = t >> 1, n = t & 1;
    const float* l = &lg[smp][n][0];
    int best = 0; float bv = l[0];
    for (int s = 1; s < SECN; s++) { float v = l[s]; if (v > bv) { bv = v; best = s; } }
    sec_idx[(blk * 4 + smp) * NN + n] = best;
  }
}

// ---------------- Kernel 2: conv encoder via split-bf16 MFMA -> feat ----------------
// LDS regions (aliased by phase):
//  [0, 20800):  act1_hi[130][40], act1_lo[130][40] shorts  -> later act2p_hi/lo[34][72]
//  [20800, 55616): in0p[512] f32 -> act2t[128][68] f32 -> act3t[32][132] f32
#define CONV_LDS 55616
__global__ __launch_bounds__(256, 2) void conv_kernel(
    const float* __restrict__ x, const int* __restrict__ sec_idx,
    const float* __restrict__ w1, const float* __restrict__ b1,
    const float* __restrict__ bn1g, const float* __restrict__ bn1b,
    const short* __restrict__ w2hi, const short* __restrict__ w2lo,
    const float* __restrict__ b2,
    const float* __restrict__ bn2g, const float* __restrict__ bn2b,
    const short* __restrict__ w3hi, const short* __restrict__ w3lo,
    const float* __restrict__ b3,
    const float* __restrict__ bn3g, const float* __restrict__ bn3b,
    float* __restrict__ feat) {
  __shared__ __align__(16) char smem[CONV_LDS];
  short* act1_hi  = (short*)smem;               // [130][40]
  short* act1_lo  = (short*)(smem + 10400);     // [130][40]
  short* act2p_hi = (short*)smem;               // [34][72]
  short* act2p_lo = (short*)(smem + 4896);      // [34][72]
  float* in0p  = (float*)(smem + 20800);        // [512]
  float* act2t = (float*)(smem + 20800);        // [128][68]
  float* act3t = (float*)(smem + 20800);        // [32][132]

  const int sample = blockIdx.x;
  const int t = threadIdx.x;
  const int bsIdx = sample >> 1;
  const float bnscale = rsqrtf(1.0f + 1e-5f);
  const int wv = t >> 6, l = t & 63, lr = l & 15, lg2 = l >> 4;

  // ---- phase 1: load x section (padded), zero act1 pad rows ----
  {
    int sec = sec_idx[sample];
    const float* src = &x[bsIdx * NSAMP + sec * HID];
    for (int i = t; i < 512; i += 256) in0p[i] = (i >= 1 && i <= 500) ? src[i - 1] : 0.f;
    if (t < 200) {
      int r = t / 40; r = (r == 0) ? 0 : 125 + r;   // rows 0,126..129
      int idx = r * 40 + t % 40;
      act1_hi[idx] = 0; act1_lo[idx] = 0;
    }
  }
  __syncthreads();

  // ---- phase 2: conv1 + relu + pool4 + bn -> act1 hi/lo bf16 [pos+1][ic] ----
  {
    int ic = t & 31;
    float w0 = w1[ic * 3], w1v = w1[ic * 3 + 1], w2v = w1[ic * 3 + 2];
    float bb = b1[ic];
    float g = bn1g[ic] * bnscale, be = bn1b[ic];
    for (int p = t >> 5; p < 125; p += 8) {
      int base = 4 * p;
      float xm1 = in0p[base], x0 = in0p[base + 1], x1 = in0p[base + 2],
            x2 = in0p[base + 3], x3 = in0p[base + 4], x4 = in0p[base + 5];
      float a0 = bb + w0 * xm1 + w1v * x0 + w2v * x1;
      float a1 = bb + w0 * x0  + w1v * x1 + w2v * x2;
      float a2 = bb + w0 * x1  + w1v * x2 + w2v * x3;
      float a3 = bb + w0 * x2  + w1v * x3 + w2v * x4;
      float m = fmaxf(fmaxf(fmaxf(fmaxf(a0, a1), a2), a3), 0.f);
      float v = m * g + be;
      short hi = f2bf(v);
      short lo = f2bf(v - bf2f(hi));
      act1_hi[(p + 1) * 40 + ic] = hi;
      act1_lo[(p + 1) * 40 + ic] = lo;
    }
  }
  __syncthreads();

  // ---- phase 3: conv2 MFMA  C[64ch][128pos] = W2[64][96] @ B2 ----
  {
    floatx4 acc[4][2];
#pragma unroll
    for (int m = 0; m < 4; m++)
#pragma unroll
      for (int nn = 0; nn < 2; nn++) acc[m][nn] = (floatx4){0.f, 0.f, 0.f, 0.f};
#pragma unroll
    for (int s = 0; s < 3; s++) {
      short8 Ah[4], Al[4], Bh[2], Bl[2];
#pragma unroll
      for (int m = 0; m < 4; m++) {
        int aoff = (m * 16 + lr) * 96 + s * 32 + lg2 * 8;
        Ah[m] = *(const short8*)(w2hi + aoff);
        Al[m] = *(const short8*)(w2lo + aoff);
      }
#pragma unroll
      for (int nn = 0; nn < 2; nn++) {
        int boff = ((2 * wv + nn) * 16 + lr + s) * 40 + lg2 * 8;
        Bh[nn] = *(const short8*)(act1_hi + boff);
        Bl[nn] = *(const short8*)(act1_lo + boff);
      }
#pragma unroll
      for (int m = 0; m < 4; m++)
#pragma unroll
        for (int nn = 0; nn < 2; nn++) {
          acc[m][nn] = __builtin_amdgcn_mfma_f32_16x16x32_bf16(Ah[m], Bh[nn], acc[m][nn], 0, 0, 0);
          acc[m][nn] = __builtin_amdgcn_mfma_f32_16x16x32_bf16(Ah[m], Bl[nn], acc[m][nn], 0, 0, 0);
          acc[m][nn] = __builtin_amdgcn_mfma_f32_16x16x32_bf16(Al[m], Bh[nn], acc[m][nn], 0, 0, 0);
        }
    }
#pragma unroll
    for (int m = 0; m < 4; m++)
#pragma unroll
      for (int nn = 0; nn < 2; nn++) {
        int p = (2 * wv + nn) * 16 + lr;
        *(floatx4*)(act2t + p * 68 + m * 16 + lg2 * 4) = acc[m][nn];
      }
  }
  __syncthreads();

  // ---- phase 4: pool5 + bias + relu + bn -> act2p hi/lo; zero pads ----
  {
    if (t < 162) {  // 9 pad rows (0,26..33) x 72, two arrays: 648 shorts / 4
      for (int i = t; i < 648; i += 162) {
        int r = i / 72; r = (r == 0) ? 0 : 25 + r;
        int idx = r * 72 + i % 72;
        act2p_hi[idx] = 0; act2p_lo[idx] = 0;
      }
    }
    int ic = t & 63;
    float bb = b2[ic], g = bn2g[ic] * bnscale, be = bn2b[ic];
    for (int pw = t >> 6; pw < 25; pw += 4) {
      int base = 5 * pw;
      float m = act2t[base * 68 + ic];
      m = fmaxf(m, act2t[(base + 1) * 68 + ic]);
      m = fmaxf(m, act2t[(base + 2) * 68 + ic]);
      m = fmaxf(m, act2t[(base + 3) * 68 + ic]);
      m = fmaxf(m, act2t[(base + 4) * 68 + ic]);
      float v = fmaxf(m + bb, 0.f) * g + be;
      short hi = f2bf(v);
      short lo = f2bf(v - bf2f(hi));
      act2p_hi[(pw + 1) * 72 + ic] = hi;
      act2p_lo[(pw + 1) * 72 + ic] = lo;
    }
  }
  __syncthreads();

  // ---- phase 5: conv3 MFMA  C[128ch][32pos] = W3[128][192] @ B3 ----
  {
    floatx4 acc[2][2];
#pragma unroll
    for (int mm = 0; mm < 2; mm++)
#pragma unroll
      for (int nn = 0; nn < 2; nn++) acc[mm][nn] = (floatx4){0.f, 0.f, 0.f, 0.f};
#pragma unroll
    for (int s = 0; s < 6; s++) {
      short8 Ah[2], Al[2], Bh[2], Bl[2];
#pragma unroll
      for (int mm = 0; mm < 2; mm++) {
        int aoff = ((wv * 2 + mm) * 16 + lr) * 192 + s * 32 + lg2 * 8;
        Ah[mm] = *(const short8*)(w3hi + aoff);
        Al[mm] = *(const short8*)(w3lo + aoff);
      }
#pragma unroll
      for (int nn = 0; nn < 2; nn++) {
        int boff = (nn * 16 + lr + (s >> 1)) * 72 + (s & 1) * 32 + lg2 * 8;
        Bh[nn] = *(const short8*)(act2p_hi + boff);
        Bl[nn] = *(const short8*)(act2p_lo + boff);
      }
#pragma unroll
      for (int mm = 0; mm < 2; mm++)
#pragma unroll
        for (int nn = 0; nn < 2; nn++) {
          acc[mm][nn] = __builtin_amdgcn_mfma_f32_16x16x32_bf16(Ah[mm], Bh[nn], acc[mm][nn], 0, 0, 0);
          acc[mm][nn] = __builtin_amdgcn_mfma_f32_16x16x32_bf16(Ah[mm], Bl[nn], acc[mm][nn], 0, 0, 0);
          acc[mm][nn] = __builtin_amdgcn_mfma_f32_16x16x32_bf16(Al[mm], Bh[nn], acc[mm][nn], 0, 0, 0);
        }
    }
#pragma unroll
    for (int mm = 0; mm < 2; mm++)
#pragma unroll
      for (int nn = 0; nn < 2; nn++) {
        int p = nn * 16 + lr;
        *(floatx4*)(act3t + p * 132 + (wv * 2 + mm) * 16 + lg2 * 4) = acc[mm][nn];
      }
  }
  __syncthreads();

  // ---- phase 6: pool4(first 24) + bias + relu + bn -> feat ----
  {
    int c = t & 127;
    float bb = b3[c], g = bn3g[c] * bnscale, be = bn3b[c];
    for (int pw = t >> 7; pw < 6; pw += 2) {
      int base = 4 * pw;
      float m = act3t[base * 132 + c];
      m = fmaxf(m, act3t[(base + 1) * 132 + c]);
      m = fmaxf(m, act3t[(base + 2) * 132 + c]);
      m = fmaxf(m, act3t[(base + 3) * 132 + c]);
      float v = fmaxf(m + bb, 0.f) * g + be;
      feat[sample * 768 + c * 6 + pw] = v;
    }
  }
}

// ---------------- Kernel 2b: fc GEMM + fc2 + proto argmin ----------------
__global__ __launch_bounds__(256, 2) void fc_kernel(
    const float* __restrict__ feat,
    const float* __restrict__ fcw, const float* __restrict__ fcb,
    const float* __restrict__ fc2w, const float* __restrict__ fc2b,
    const float* __restrict__ protos, int* __restrict__ proto_idx) {
  __shared__ __align__(16) float a_sh[FCSAMP * 768];
  __shared__ __align__(16) float fco[FCSAMP * 256];
  __shared__ __align__(16) float zsh[FCSAMP * 128];
  __shared__ float d2[FCSAMP][NPROTO];

  const int blk = blockIdx.x;
  const int t = threadIdx.x;
  const int s0 = blk * FCSAMP;

  for (int e = t; e < FCSAMP * 192; e += 256) {
    reinterpret_cast<float4*>(a_sh)[e] =
        reinterpret_cast<const float4*>(feat)[s0 * 192 + e];
  }
  __syncthreads();

  {
    float acc[FCSAMP];
    float bb = fcb[t];
#pragma unroll
    for (int m = 0; m < FCSAMP; m++) acc[m] = bb;
    for (int i = 0; i < 768; i++) {
      float wvv = fcw[i * 256 + t];
#pragma unroll
      for (int m = 0; m < FCSAMP; m++)
        acc[m] += a_sh[m * 768 + i] * wvv;
    }
#pragma unroll
    for (int m = 0; m < FCSAMP; m++) fco[m * 256 + t] = acc[m];
  }
  __syncthreads();

  if (t < 128) {
    float acc[FCSAMP];
    float bb = fc2b[t];
#pragma unroll
    for (int m = 0; m < FCSAMP; m++) acc[m] = bb;
    for (int i = 0; i < 256; i++) {
      float wvv = fc2w[i * 128 + t];
#pragma unroll
      for (int m = 0; m < FCSAMP; m++)
        acc[m] += fco[m * 256 + i] * wvv;
    }
#pragma unroll
    for (int m = 0; m < FCSAMP; m++) zsh[m * 128 + t] = acc[m];
  }
  __syncthreads();

  for (int o = t; o < FCSAMP * NPROTO; o += 256) {
    int m = o / NPROTO, pi = o % NPROTO;
    const float4* pp = reinterpret_cast<const float4*>(protos + pi * OUTD);
    const float4* zz = reinterpret_cast<const float4*>(zsh + m * OUTD);
    float acc = 0.f;
    for (int i4 = 0; i4 < 32; i4++) {
      float4 p4 = pp[i4], z4 = zz[i4];
      acc += p4.x * (p4.x - 2.f * z4.x) + p4.y * (p4.y - 2.f * z4.y)
           + p4.z * (p4.z - 2.f * z4.z) + p4.w * (p4.w - 2.f * z4.w);
    }
    d2[m][pi] = acc;
  }
  __syncthreads();
  if (t < FCSAMP) {
    int best = 0; float bv = d2[t][0];
    for (int i = 1; i < NPROTO; i++) { float v = d2[t][i]; if (v < bv) { bv = v; best = i; } }
    proto_idx[s0 + t] = best;
  }
}

// ---------------- Kernel 3: sequence transformer + classifier ----------------
__global__ __launch_bounds__(512) void seq_kernel(
    const int* __restrict__ proto_idx, const float* __restrict__ protos,
    const float* __restrict__ inw, const float* __restrict__ inb,
    const float* __restrict__ outw, const float* __restrict__ outb,
    const float* __restrict__ ln1g, const float* __restrict__ ln1b,
    const float* __restrict__ ln2g, const float* __restrict__ ln2b,
    const float* __restrict__ ff1w, const float* __restrict__ ff1b,
    const float* __restrict__ ff2w, const float* __restrict__ ff2b,
    const float* __restrict__ clfw, const float* __restrict__ clfb,
    float* __restrict__ out) {
  __shared__ __align__(16) float hsh[SS * OUTD];
  __shared__ __align__(16) float big[SS * 3 * OUTD];
  __shared__ __align__(16) float sc[NHEAD * SS * SS];
  __shared__ __align__(16) float ctx[SS * OUTD];
  __shared__ float rowm[SS], rowv[SS];

  const int b = blockIdx.x;
  const int t = threadIdx.x;

  for (int o = t; o < SS * OUTD; o += 512) {
    int s = o >> 7, d = o & 127;
    int i0 = proto_idx[(b * SS + s) * 2];
    int i1 = proto_idx[(b * SS + s) * 2 + 1];
    float pc = 0.5f * (protos[i0 * OUTD + d] + protos[i1 * OUTD + d]);
    int i = d >> 1;
    float div = expf((float)(2 * i) * -0.07195578415606439f);
    float ang = (float)s * div;
    float pe = (d & 1) ? cosf(ang) : sinf(ang);
    hsh[o] = pc + pe;
  }
  __syncthreads();

  for (int o = t; o < SS * 384; o += 512) {
    int s = o / 384, j = o % 384;
    float4 a4 = make_float4(0.f, 0.f, 0.f, 0.f);
    const float4* hr = reinterpret_cast<const float4*>(&hsh[s * OUTD]);
    for (int d4 = 0; d4 < 32; d4++) {
      float4 h4 = hr[d4];
      int d = d4 * 4;
      a4.x += h4.x * inw[(d + 0) * 384 + j];
      a4.y += h4.y * inw[(d + 1) * 384 + j];
      a4.z += h4.z * inw[(d + 2) * 384 + j];
      a4.w += h4.w * inw[(d + 3) * 384 + j];
    }
    big[o] = inb[j] + ((a4.x + a4.y) + (a4.z + a4.w));
  }
  __syncthreads();

  for (int o = t; o < NHEAD * SS * SS; o += 512) {
    int hd = o / (SS * SS), r = o % (SS * SS), qs = r / SS, ks = r % SS;
    const float4* qp = reinterpret_cast<const float4*>(&big[qs * 384 + hd * 32]);
    const float4* kp = reinterpret_cast<const float4*>(&big[ks * 384 + 128 + hd * 32]);
    float4 a4 = make_float4(0.f, 0.f, 0.f, 0.f);
#pragma unroll
    for (int d4 = 0; d4 < 8; d4++) {
      float4 q4 = qp[d4], k4 = kp[d4];
      a4.x += q4.x * k4.x; a4.y += q4.y * k4.y; a4.z += q4.z * k4.z; a4.w += q4.w * k4.w;
    }
    sc[o] = ((a4.x + a4.y) + (a4.z + a4.w)) * 0.17677669529663689f;
  }
  __syncthreads();
  for (int r = t; r < NHEAD * SS; r += 512) {
    float* row = &sc[r * SS];
    float mx = row[0];
    for (int i = 1; i < SS; i++) mx = fmaxf(mx, row[i]);
    float sum = 0.f;
    for (int i = 0; i < SS; i++) { float e = expf(row[i] - mx); row[i] = e; sum += e; }
    float inv = 1.f / sum;
    for (int i = 0; i < SS; i++) row[i] *= inv;
  }
  __syncthreads();
  for (int o = t; o < SS * OUTD; o += 512) {
    int qs = o >> 7, d = o & 127, hd = d >> 5, dd = d & 31;
    const float* srow = &sc[(hd * SS + qs) * SS];
    float a = 0.f;
    for (int ks = 0; ks < SS; ks++) a += srow[ks] * big[ks * 384 + 256 + hd * 32 + dd];
    ctx[o] = a;
  }
  __syncthreads();
  float* tmp = big;
  for (int o = t; o < SS * OUTD; o += 512) {
    int s = o >> 7, d = o & 127;
    float4 a4 = make_float4(0.f, 0.f, 0.f, 0.f);
    const float4* cr = reinterpret_cast<const float4*>(&ctx[s * OUTD]);
    for (int e4 = 0; e4 < 32; e4++) {
      float4 c4 = cr[e4];
      int e = e4 * 4;
      a4.x += c4.x * outw[(e + 0) * OUTD + d];
      a4.y += c4.y * outw[(e + 1) * OUTD + d];
      a4.z += c4.z * outw[(e + 2) * OUTD + d];
      a4.w += c4.w * outw[(e + 3) * OUTD + d];
    }
    tmp[o] = hsh[o] + outb[d] + ((a4.x + a4.y) + (a4.z + a4.w));
  }
  __syncthreads();
  if (t < SS) {
    const float4* r4 = reinterpret_cast<const float4*>(&tmp[t * OUTD]);
    float4 m4 = make_float4(0.f, 0.f, 0.f, 0.f);
    for (int d4 = 0; d4 < 32; d4++) {
      float4 v = r4[d4];
      m4.x += v.x; m4.y += v.y; m4.z += v.z; m4.w += v.w;
    }
    float m = ((m4.x + m4.y) + (m4.z + m4.w)) * (1.0f / OUTD);
    float4 v4 = make_float4(0.f, 0.f, 0.f, 0.f);
    for (int d4 = 0; d4 < 32; d4++) {
      float4 v = r4[d4];
      float ux = v.x - m, uy = v.y - m, uz = v.z - m, uw = v.w - m;
      v4.x += ux * ux; v4.y += uy * uy; v4.z += uz * uz; v4.w += uw * uw;
    }
    float var = ((v4.x + v4.y) + (v4.z + v4.w)) * (1.0f / OUTD);
    rowm[t] = m; rowv[t] = rsqrtf(var + 1e-5f);
  }
  __syncthreads();
  for (int o = t; o < SS * OUTD; o += 512) {
    int s = o >> 7, d = o & 127;
    hsh[o] = (tmp[o] - rowm[s]) * rowv[s] * ln1g[d] + ln1b[d];
  }
  __syncthreads();
  for (int o = t; o < SS * OUTD; o += 512) {
    int s = o >> 7, d = o & 127;
    float4 a4 = make_float4(0.f, 0.f, 0.f, 0.f);
    const float4* hr = reinterpret_cast<const float4*>(&hsh[s * OUTD]);
    for (int e4 = 0; e4 < 32; e4++) {
      float4 h4 = hr[e4];
      int e = e4 * 4;
      a4.x += h4.x * ff1w[(e + 0) * OUTD + d];
      a4.y += h4.y * ff1w[(e + 1) * OUTD + d];
      a4.z += h4.z * ff1w[(e + 2) * OUTD + d];
      a4.w += h4.w * ff1w[(e + 3) * OUTD + d];
    }
    ctx[o] = fmaxf(ff1b[d] + ((a4.x + a4.y) + (a4.z + a4.w)), 0.f);
  }
  __syncthreads();
  for (int o = t; o < SS * OUTD; o += 512) {
    int s = o >> 7, d = o & 127;
    float4 a4 = make_float4(0.f, 0.f, 0.f, 0.f);
    const float4* cr = reinterpret_cast<const float4*>(&ctx[s * OUTD]);
    for (int e4 = 0; e4 < 32; e4++) {
      float4 c4 = cr[e4];
      int e = e4 * 4;
      a4.x += c4.x * ff2w[(e + 0) * OUTD + d];
      a4.y += c4.y * ff2w[(e + 1) * OUTD + d];
      a4.z += c4.z * ff2w[(e + 2) * OUTD + d];
      a4.w += c4.w * ff2w[(e + 3) * OUTD + d];
    }
    tmp[o] = hsh[o] + ff2b[d] + ((a4.x + a4.y) + (a4.z + a4.w));
  }
  __syncthreads();
  if (t < SS) {
    const float4* r4 = reinterpret_cast<const float4*>(&tmp[t * OUTD]);
    float4 m4 = make_float4(0.f, 0.f, 0.f, 0.f);
    for (int d4 = 0; d4 < 32; d4++) {
      float4 v = r4[d4];
      m4.x += v.x; m4.y += v.y; m4.z += v.z; m4.w += v.w;
    }
    float m = ((m4.x + m4.y) + (m4.z + m4.w)) * (1.0f / OUTD);
    float4 v4 = make_float4(0.f, 0.f, 0.f, 0.f);
    for (int d4 = 0; d4 < 32; d4++) {
      float4 v = r4[d4];
      float ux = v.x - m, uy = v.y - m, uz = v.z - m, uw = v.w - m;
      v4.x += ux * ux; v4.y += uy * uy; v4.z += uz * uz; v4.w += uw * uw;
    }
    float var = ((v4.x + v4.y) + (v4.z + v4.w)) * (1.0f / OUTD);
    rowm[t] = m; rowv[t] = rsqrtf(var + 1e-5f);
  }
  __syncthreads();
  for (int o = t; o < SS * OUTD; o += 512) {
    int s = o >> 7, d = o & 127;
    hsh[o] = (tmp[o] - rowm[s]) * rowv[s] * ln2g[d] + ln2b[d];
  }
  __syncthreads();
  for (int o = t; o < SS * NCLS; o += 512) {
    int s = o / NCLS, c = o % NCLS;
    float4 a4 = make_float4(0.f, 0.f, 0.f, 0.f);
    const float4* hr = reinterpret_cast<const float4*>(&hsh[s * OUTD]);
    for (int d4 = 0; d4 < 32; d4++) {
      float4 h4 = hr[d4];
      int d = d4 * 4;
      a4.x += h4.x * clfw[(d + 0) * NCLS + c];
      a4.y += h4.y * clfw[(d + 1) * NCLS + c];
      a4.z += h4.z * clfw[(d + 2) * NCLS + c];
      a4.w += h4.w * clfw[(d + 3) * NCLS + c];
    }
    out[(b * SS + s) * NCLS + c] = clfb[c] + ((a4.x + a4.y) + (a4.z + a4.w));
  }
}

extern "C" void kernel_launch(void* const* d_in, const int* in_sizes, int n_in,
                              void* d_out, int out_size, void* d_ws, size_t ws_size,
                              hipStream_t stream) {
  const float* x     = (const float*)d_in[0];
  const float* gum   = (const float*)d_in[1];
  const float* wq    = (const float*)d_in[2];
  const float* wk    = (const float*)d_in[3];
  const float* w1    = (const float*)d_in[4];
  const float* b1    = (const float*)d_in[5];
  const float* bn1g  = (const float*)d_in[6];
  const float* bn1b  = (const float*)d_in[7];
  const float* w2    = (const float*)d_in[8];
  const float* b2    = (const float*)d_in[9];
  const float* bn2g  = (const float*)d_in[10];
  const float* bn2b  = (const float*)d_in[11];
  const float* w3    = (const float*)d_in[12];
  const float* b3    = (const float*)d_in[13];
  const float* bn3g  = (const float*)d_in[14];
  const float* bn3b  = (const float*)d_in[15];
  const float* fcw   = (const float*)d_in[16];
  const float* fcb   = (const float*)d_in[17];
  const float* fc2w  = (const float*)d_in[18];
  const float* fc2b  = (const float*)d_in[19];
  const float* prot  = (const float*)d_in[20];
  const float* inw   = (const float*)d_in[21];
  const float* inb   = (const float*)d_in[22];
  const float* outw  = (const float*)d_in[23];
  const float* outb  = (const float*)d_in[24];
  const float* ln1g  = (const float*)d_in[25];
  const float* ln1b  = (const float*)d_in[26];
  const float* ln2g  = (const float*)d_in[27];
  const float* ln2b  = (const float*)d_in[28];
  const float* ff1w  = (const float*)d_in[29];
  const float* ff1b  = (const float*)d_in[30];
  const float* ff2w  = (const float*)d_in[31];
  const float* ff2b  = (const float*)d_in[32];
  const float* clfw  = (const float*)d_in[33];
  const float* clfb  = (const float*)d_in[34];
  float* out = (float*)d_out;

  int* sec_idx   = (int*)d_ws;
  int* proto_idx = sec_idx + NSAMPLE;
  short* w2hi = (short*)((float*)d_ws + WS_W2HI);
  short* w2lo = (short*)((float*)d_ws + WS_W2LO);
  short* w3hi = (short*)((float*)d_ws + WS_W3HI);
  short* w3lo = (short*)((float*)d_ws + WS_W3LO);
  float* feat = (float*)d_ws + WS_FEAT;

  hipLaunchKernelGGL(prep_kernel, dim3(120), dim3(256), 0, stream,
                     w2, w3, w2hi, w2lo, w3hi, w3lo);
  hipLaunchKernelGGL(attn_kernel, dim3(BS / 4), dim3(512), 0, stream,
                     x, gum, wq, wk, sec_idx);
  hipLaunchKernelGGL(conv_kernel, dim3(NSAMPLE), dim3(256), 0, stream,
                     x, sec_idx, w1, b1, bn1g, bn1b, w2hi, w2lo, b2, bn2g, bn2b,
                     w3hi, w3lo, b3, bn3g, bn3b, feat);
  hipLaunchKernelGGL(fc_kernel, dim3(NSAMPLE / FCSAMP), dim3(256), 0, stream,
                     feat, fcw, fcb, fc2w, fc2b, prot, proto_idx);
  hipLaunchKernelGGL(seq_kernel, dim3(BB), dim3(512), 0, stream,
                     proto_idx, prot, inw, inb, outw, outb,
                     ln1g, ln1b, ln2g, ln2b, ff1w, ff1b, ff2w, ff2b,
                     clfw, clfb, out);
}

// Round 4
// 252.292 us; speedup vs baseline: 3.4907x; 1.1666x over previous
//
#include <hip/hip_runtime.h>
#include <math.h>

#define BB 64
#define SS 21
#define NSAMP 3000
#define HID 500
#define SECN 6
#define NN 2
#define OUTD 128
#define NPROTO 25
#define NCLS 5
#define NHEAD 4
#define BS (BB*SS)          // 1344
#define NSAMPLE (BS*NN)     // 2688

// ws float offsets
#define WS_W2HI 5376
#define WS_W2LO 8448
#define WS_W3HI 11520
#define WS_W3LO 23808
#define WS_P3   36096
#define WS_C3   (WS_P3 + 19200)

typedef __attribute__((ext_vector_type(8))) short short8;
typedef __attribute__((ext_vector_type(4))) float floatx4;

__device__ __forceinline__ short f2bf(float f) {
  unsigned u = __float_as_uint(f);
  u += 0x7FFF + ((u >> 16) & 1);          // RNE to bf16
  return (short)(u >> 16);
}
__device__ __forceinline__ float bf2f(short h) {
  return __uint_as_float(((unsigned)(unsigned short)h) << 16);
}

// ---------------- Kernel 0: weight hi/lo bf16 splits into ws ----------------
__global__ __launch_bounds__(256) void prep_kernel(
    const float* __restrict__ w2, const float* __restrict__ w3,
    short* __restrict__ w2hi, short* __restrict__ w2lo,
    short* __restrict__ w3hi, short* __restrict__ w3lo) {
  int idx = blockIdx.x * 256 + threadIdx.x;
  if (idx < 6144) {
    int ic = idx & 31, ck = idx >> 5, k = ck % 3, c = ck / 3;
    float v = w2[c * 96 + ic * 3 + k];
    int dst = c * 96 + k * 32 + ic;         // K = k*32+ic
    short hi = f2bf(v);
    short lo = f2bf(v - bf2f(hi));
    w2hi[dst] = hi; w2lo[dst] = lo;
  } else if (idx < 30720) {
    int j = idx - 6144;
    int ic = j & 63, ck = j >> 6, k = ck % 3, c = ck / 3;
    float v = w3[(c * 64 + ic) * 3 + k];
    int dst = c * 192 + k * 64 + ic;        // K = k*64+ic
    short hi = f2bf(v);
    short lo = f2bf(v - bf2f(hi));
    w3hi[dst] = hi; w3lo[dst] = lo;
  }
}

// ---------------- Kernel 0b: fold fc/fc2/protos into P3, c3 ----------------
// score[p] = P3[p].feat + c3[p];  argmax_p score  ==  argmin_p ||z - proto_p||^2
__global__ __launch_bounds__(256) void prep2_kernel(
    const float* __restrict__ protos, const float* __restrict__ fc2w,
    const float* __restrict__ fcw, const float* __restrict__ fcb,
    const float* __restrict__ fc2b,
    float* __restrict__ P3, float* __restrict__ c3) {
  __shared__ __align__(16) float p2row[256];
  __shared__ float red[256];
  const int p = blockIdx.x, j = threadIdx.x;

  // P2[p][j] = sum_c protos[p][c] * fc2w[j][c]
  {
    const float4* pr = reinterpret_cast<const float4*>(protos + p * 128);
    const float4* wr = reinterpret_cast<const float4*>(fc2w + j * 128);
    float4 a4 = make_float4(0.f, 0.f, 0.f, 0.f);
    for (int c4 = 0; c4 < 32; c4++) {
      float4 a = pr[c4], b = wr[c4];
      a4.x += a.x * b.x; a4.y += a.y * b.y; a4.z += a.z * b.z; a4.w += a.w * b.w;
    }
    float v = (a4.x + a4.y) + (a4.z + a4.w);
    p2row[j] = v;
    float contrib = v * fcb[j];
    if (j < 128) {
      float pv = protos[p * 128 + j];
      contrib += pv * fc2b[j] - 0.5f * pv * pv;
    }
    red[j] = contrib;
  }
  __syncthreads();
  for (int s = 128; s > 0; s >>= 1) {
    if (j < s) red[j] += red[j + s];
    __syncthreads();
  }
  if (j == 0) c3[p] = red[0];

  // P3[p][k] = sum_j p2row[j] * fcw[k][j]
  for (int k = j; k < 768; k += 256) {
    const float4* fr = reinterpret_cast<const float4*>(fcw + k * 256);
    const float4* p2 = reinterpret_cast<const float4*>(p2row);
    float4 a4 = make_float4(0.f, 0.f, 0.f, 0.f);
    for (int j4 = 0; j4 < 64; j4++) {
      float4 a = p2[j4], b = fr[j4];
      a4.x += a.x * b.x; a4.y += a.y * b.y; a4.z += a.z * b.z; a4.w += a.w * b.w;
    }
    P3[p * 768 + k] = (a4.x + a4.y) + (a4.z + a4.w);
  }
}

// ---------------- Kernel 1: hard attention -> section index ----------------
__global__ __launch_bounds__(512, 4) void attn_kernel(
    const float* __restrict__ x, const float* __restrict__ gumbel,
    const float* __restrict__ wq, const float* __restrict__ wk,
    int* __restrict__ sec_idx) {
  __shared__ __align__(16) float xp[4 * SECN * HID];
  __shared__ __align__(16) float xsum[4 * HID];
  __shared__ __align__(16) float ks[4 * 256];
  __shared__ __align__(16) float vbuf[4 * 2 * HID];
  __shared__ float lg[4][NN][SECN];
  const int blk = blockIdx.x;
  const int t = threadIdx.x;
  float4* xpf4 = reinterpret_cast<float4*>(xp);
  float4* xsf4 = reinterpret_cast<float4*>(xsum);
  float4* ksf4 = reinterpret_cast<float4*>(ks);
  float4* vf4  = reinterpret_cast<float4*>(vbuf);

  for (int e = t; e < 4 * SECN * 125; e += 512) {
    int rem = e % 750, s = rem / 125, h4 = rem % 125;
    float4 xv = reinterpret_cast<const float4*>(x)[blk * 3000 + e];
    float4 o;
    float* ov = (float*)&o; const float* iv = (const float*)&xv;
#pragma unroll
    for (int j = 0; j < 4; j++) {
      int h = h4 * 4 + j;
      int i = h >> 1;
      float div = expf((float)(2 * i) * -0.0184206807439523674f);
      float ang = (float)s * div;
      float pe = (h & 1) ? cosf(ang) : sinf(ang);
      ov[j] = iv[j] + pe;
    }
    xpf4[e] = o;
  }
  __syncthreads();

  if (t < 500) {
    int smp = t / 125, h4 = t % 125;
    float4 a = xpf4[(smp * 6 + 0) * 125 + h4];
#pragma unroll
    for (int s = 1; s < SECN; s++) {
      float4 b = xpf4[(smp * 6 + s) * 125 + h4];
      a.x += b.x; a.y += b.y; a.z += b.z; a.w += b.w;
    }
    xsf4[smp * 125 + h4] = a;
  }
  __syncthreads();

  {
    float* ksp = vbuf;
    int col = t & 255, hh = t >> 8;
    int b4 = hh ? 62 : 0, e4 = hh ? 125 : 62;
    float4 acc0 = make_float4(0.f,0.f,0.f,0.f), acc1 = acc0, acc2 = acc0, acc3 = acc0;
    for (int h4 = b4; h4 < e4; h4++) {
      int h = h4 * 4;
      float w0 = wk[(h + 0) * 256 + col];
      float w1 = wk[(h + 1) * 256 + col];
      float w2 = wk[(h + 2) * 256 + col];
      float w3 = wk[(h + 3) * 256 + col];
      float4 xs0 = xsf4[0 * 125 + h4];
      float4 xs1 = xsf4[1 * 125 + h4];
      float4 xs2 = xsf4[2 * 125 + h4];
      float4 xs3 = xsf4[3 * 125 + h4];
      acc0.x += xs0.x * w0; acc0.y += xs0.y * w1; acc0.z += xs0.z * w2; acc0.w += xs0.w * w3;
      acc1.x += xs1.x * w0; acc1.y += xs1.y * w1; acc1.z += xs1.z * w2; acc1.w += xs1.w * w3;
      acc2.x += xs2.x * w0; acc2.y += xs2.y * w1; acc2.z += xs2.z * w2; acc2.w += xs2.w * w3;
      acc3.x += xs3.x * w0; acc3.y += xs3.y * w1; acc3.z += xs3.z * w2; acc3.w += xs3.w * w3;
    }
    ksp[hh * 1024 + 0 * 256 + col] = (acc0.x + acc0.y) + (acc0.z + acc0.w);
    ksp[hh * 1024 + 1 * 256 + col] = (acc1.x + acc1.y) + (acc1.z + acc1.w);
    ksp[hh * 1024 + 2 * 256 + col] = (acc2.x + acc2.y) + (acc2.z + acc2.w);
    ksp[hh * 1024 + 3 * 256 + col] = (acc3.x + acc3.y) + (acc3.z + acc3.w);
  }
  __syncthreads();
  for (int e = t; e < 1024; e += 512) ks[e] = vbuf[e] + vbuf[1024 + e];
  __syncthreads();

  if (t < 500) {
    int h = t;
    const float4* wqr = reinterpret_cast<const float4*>(wq + h * 256);
    float4 accA0 = make_float4(0.f,0.f,0.f,0.f), accA1 = accA0, accA2 = accA0, accA3 = accA0;
    for (int c4 = 0; c4 < 32; c4++) {
      float4 wv = wqr[c4];
      float4 k0 = ksf4[0 * 64 + c4], k1 = ksf4[1 * 64 + c4];
      float4 k2 = ksf4[2 * 64 + c4], k3 = ksf4[3 * 64 + c4];
      accA0.x += wv.x*k0.x; accA0.y += wv.y*k0.y; accA0.z += wv.z*k0.z; accA0.w += wv.w*k0.w;
      accA1.x += wv.x*k1.x; accA1.y += wv.y*k1.y; accA1.z += wv.z*k1.z; accA1.w += wv.w*k1.w;
      accA2.x += wv.x*k2.x; accA2.y += wv.y*k2.y; accA2.z += wv.z*k2.z; accA2.w += wv.w*k2.w;
      accA3.x += wv.x*k3.x; accA3.y += wv.y*k3.y; accA3.z += wv.z*k3.z; accA3.w += wv.w*k3.w;
    }
    float4 accB0 = make_float4(0.f,0.f,0.f,0.f), accB1 = accB0, accB2 = accB0, accB3 = accB0;
    for (int c4 = 32; c4 < 64; c4++) {
      float4 wv = wqr[c4];
      float4 k0 = ksf4[0 * 64 + c4], k1 = ksf4[1 * 64 + c4];
      float4 k2 = ksf4[2 * 64 + c4], k3 = ksf4[3 * 64 + c4];
      accB0.x += wv.x*k0.x; accB0.y += wv.y*k0.y; accB0.z += wv.z*k0.z; accB0.w += wv.w*k0.w;
      accB1.x += wv.x*k1.x; accB1.y += wv.y*k1.y; accB1.z += wv.z*k1.z; accB1.w += wv.w*k1.w;
      accB2.x += wv.x*k2.x; accB2.y += wv.y*k2.y; accB2.z += wv.z*k2.z; accB2.w += wv.w*k2.w;
      accB3.x += wv.x*k3.x; accB3.y += wv.y*k3.y; accB3.z += wv.z*k3.z; accB3.w += wv.w*k3.w;
    }
    vbuf[(0 * 2 + 0) * 500 + h] = (accA0.x + accA0.y) + (accA0.z + accA0.w);
    vbuf[(1 * 2 + 0) * 500 + h] = (accA1.x + accA1.y) + (accA1.z + accA1.w);
    vbuf[(2 * 2 + 0) * 500 + h] = (accA2.x + accA2.y) + (accA2.z + accA2.w);
    vbuf[(3 * 2 + 0) * 500 + h] = (accA3.x + accA3.y) + (accA3.z + accA3.w);
    vbuf[(0 * 2 + 1) * 500 + h] = (accB0.x + accB0.y) + (accB0.z + accB0.w);
    vbuf[(1 * 2 + 1) * 500 + h] = (accB1.x + accB1.y) + (accB1.z + accB1.w);
    vbuf[(2 * 2 + 1) * 500 + h] = (accB2.x + accB2.y) + (accB2.z + accB2.w);
    vbuf[(3 * 2 + 1) * 500 + h] = (accB3.x + accB3.y) + (accB3.z + accB3.w);
  }
  __syncthreads();

  if (t < 384) {
    int item = t >> 3, part = t & 7;
    int smp = item / 12, n = (item % 12) / SECN, s = item % SECN;
    int beg = part * 16, end = beg + 16 > 125 ? 125 : beg + 16;
    const float4* xr = xpf4 + (smp * 6 + s) * 125;
    const float4* vr = vf4 + (smp * 2 + n) * 125;
    float4 a4 = make_float4(0.f,0.f,0.f,0.f);
    for (int h4 = beg; h4 < end; h4++) {
      float4 xv = xr[h4], vv = vr[h4];
      a4.x += xv.x * vv.x; a4.y += xv.y * vv.y; a4.z += xv.z * vv.z; a4.w += xv.w * vv.w;
    }
    float a = (a4.x + a4.y) + (a4.z + a4.w);
    a += __shfl_xor(a, 1);
    a += __shfl_xor(a, 2);
    a += __shfl_xor(a, 4);
    if (part == 0)
      lg[smp][n][s] = a * 0.00745355992499929898f
                    + gumbel[((blk * 4 + smp) * NN + n) * SECN + s];
  }
  __syncthreads();
  if (t < 8) {
    int smp = t >> 1, n = t & 1;
    const float* l = &lg[smp][n][0];
    int best = 0; float bv = l[0];
    for (int s = 1; s < SECN; s++) { float v = l[s]; if (v > bv) { bv = v; best = s; } }
    sec_idx[(blk * 4 + smp) * NN + n] = best;
  }
}

// ---------------- Kernel 2: conv encoder (MFMA) + folded VQ argmax ----------------
#define CONV_LDS 55616
__global__ __launch_bounds__(256, 2) void conv_kernel(
    const float* __restrict__ x, const int* __restrict__ sec_idx,
    const float* __restrict__ w1, const float* __restrict__ b1,
    const float* __restrict__ bn1g, const float* __restrict__ bn1b,
    const short* __restrict__ w2hi, const short* __restrict__ w2lo,
    const float* __restrict__ b2,
    const float* __restrict__ bn2g, const float* __restrict__ bn2b,
    const short* __restrict__ w3hi, const short* __restrict__ w3lo,
    const float* __restrict__ b3,
    const float* __restrict__ bn3g, const float* __restrict__ bn3b,
    const float* __restrict__ P3, const float* __restrict__ c3,
    int* __restrict__ proto_idx) {
  __shared__ __align__(16) char smem[CONV_LDS];
  __shared__ __align__(16) float featsh[768];
  __shared__ float sc25[NPROTO];
  short* act1_hi  = (short*)smem;               // [130][40]
  short* act1_lo  = (short*)(smem + 10400);     // [130][40]
  short* act2p_hi = (short*)smem;               // [34][72]
  short* act2p_lo = (short*)(smem + 4896);      // [34][72]
  float* in0p  = (float*)(smem + 20800);        // [512]
  float* act2t = (float*)(smem + 20800);        // [128][68]
  float* act3t = (float*)(smem + 20800);        // [32][132]

  const int sample = blockIdx.x;
  const int t = threadIdx.x;
  const int bsIdx = sample >> 1;
  const float bnscale = rsqrtf(1.0f + 1e-5f);
  const int wv = t >> 6, l = t & 63, lr = l & 15, lg2 = l >> 4;

  // ---- phase 1: load x section (padded), zero act1 pad rows ----
  {
    int sec = sec_idx[sample];
    const float* src = &x[bsIdx * NSAMP + sec * HID];
    for (int i = t; i < 512; i += 256) in0p[i] = (i >= 1 && i <= 500) ? src[i - 1] : 0.f;
    if (t < 200) {
      int r = t / 40; r = (r == 0) ? 0 : 125 + r;   // rows 0,126..129
      int idx = r * 40 + t % 40;
      act1_hi[idx] = 0; act1_lo[idx] = 0;
    }
  }
  __syncthreads();

  // ---- phase 2: conv1 + relu + pool4 + bn -> act1 hi/lo bf16 [pos+1][ic] ----
  {
    int ic = t & 31;
    float w0 = w1[ic * 3], w1v = w1[ic * 3 + 1], w2v = w1[ic * 3 + 2];
    float bb = b1[ic];
    float g = bn1g[ic] * bnscale, be = bn1b[ic];
    for (int p = t >> 5; p < 125; p += 8) {
      int base = 4 * p;
      float xm1 = in0p[base], x0 = in0p[base + 1], x1 = in0p[base + 2],
            x2 = in0p[base + 3], x3 = in0p[base + 4], x4 = in0p[base + 5];
      float a0 = bb + w0 * xm1 + w1v * x0 + w2v * x1;
      float a1 = bb + w0 * x0  + w1v * x1 + w2v * x2;
      float a2 = bb + w0 * x1  + w1v * x2 + w2v * x3;
      float a3 = bb + w0 * x2  + w1v * x3 + w2v * x4;
      float m = fmaxf(fmaxf(fmaxf(fmaxf(a0, a1), a2), a3), 0.f);
      float v = m * g + be;
      short hi = f2bf(v);
      short lo = f2bf(v - bf2f(hi));
      act1_hi[(p + 1) * 40 + ic] = hi;
      act1_lo[(p + 1) * 40 + ic] = lo;
    }
  }
  __syncthreads();

  // ---- phase 3: conv2 MFMA  C[64ch][128pos] = W2[64][96] @ B2 ----
  {
    floatx4 acc[4][2];
#pragma unroll
    for (int m = 0; m < 4; m++)
#pragma unroll
      for (int nn = 0; nn < 2; nn++) acc[m][nn] = (floatx4){0.f, 0.f, 0.f, 0.f};
#pragma unroll
    for (int s = 0; s < 3; s++) {
      short8 Ah[4], Al[4], Bh[2], Bl[2];
#pragma unroll
      for (int m = 0; m < 4; m++) {
        int aoff = (m * 16 + lr) * 96 + s * 32 + lg2 * 8;
        Ah[m] = *(const short8*)(w2hi + aoff);
        Al[m] = *(const short8*)(w2lo + aoff);
      }
#pragma unroll
      for (int nn = 0; nn < 2; nn++) {
        int boff = ((2 * wv + nn) * 16 + lr + s) * 40 + lg2 * 8;
        Bh[nn] = *(const short8*)(act1_hi + boff);
        Bl[nn] = *(const short8*)(act1_lo + boff);
      }
#pragma unroll
      for (int m = 0; m < 4; m++)
#pragma unroll
        for (int nn = 0; nn < 2; nn++) {
          acc[m][nn] = __builtin_amdgcn_mfma_f32_16x16x32_bf16(Ah[m], Bh[nn], acc[m][nn], 0, 0, 0);
          acc[m][nn] = __builtin_amdgcn_mfma_f32_16x16x32_bf16(Ah[m], Bl[nn], acc[m][nn], 0, 0, 0);
          acc[m][nn] = __builtin_amdgcn_mfma_f32_16x16x32_bf16(Al[m], Bh[nn], acc[m][nn], 0, 0, 0);
        }
    }
#pragma unroll
    for (int m = 0; m < 4; m++)
#pragma unroll
      for (int nn = 0; nn < 2; nn++) {
        int p = (2 * wv + nn) * 16 + lr;
        *(floatx4*)(act2t + p * 68 + m * 16 + lg2 * 4) = acc[m][nn];
      }
  }
  __syncthreads();

  // ---- phase 4: pool5 + bias + relu + bn -> act2p hi/lo; zero pads ----
  {
    if (t < 162) {
      for (int i = t; i < 648; i += 162) {
        int r = i / 72; r = (r == 0) ? 0 : 25 + r;
        int idx = r * 72 + i % 72;
        act2p_hi[idx] = 0; act2p_lo[idx] = 0;
      }
    }
    int ic = t & 63;
    float bb = b2[ic], g = bn2g[ic] * bnscale, be = bn2b[ic];
    for (int pw = t >> 6; pw < 25; pw += 4) {
      int base = 5 * pw;
      float m = act2t[base * 68 + ic];
      m = fmaxf(m, act2t[(base + 1) * 68 + ic]);
      m = fmaxf(m, act2t[(base + 2) * 68 + ic]);
      m = fmaxf(m, act2t[(base + 3) * 68 + ic]);
      m = fmaxf(m, act2t[(base + 4) * 68 + ic]);
      float v = fmaxf(m + bb, 0.f) * g + be;
      short hi = f2bf(v);
      short lo = f2bf(v - bf2f(hi));
      act2p_hi[(pw + 1) * 72 + ic] = hi;
      act2p_lo[(pw + 1) * 72 + ic] = lo;
    }
  }
  __syncthreads();

  // ---- phase 5: conv3 MFMA  C[128ch][32pos] = W3[128][192] @ B3 ----
  {
    floatx4 acc[2][2];
#pragma unroll
    for (int mm = 0; mm < 2; mm++)
#pragma unroll
      for (int nn = 0; nn < 2; nn++) acc[mm][nn] = (floatx4){0.f, 0.f, 0.f, 0.f};
#pragma unroll
    for (int s = 0; s < 6; s++) {
      short8 Ah[2], Al[2], Bh[2], Bl[2];
#pragma unroll
      for (int mm = 0; mm < 2; mm++) {
        int aoff = ((wv * 2 + mm) * 16 + lr) * 192 + s * 32 + lg2 * 8;
        Ah[mm] = *(const short8*)(w3hi + aoff);
        Al[mm] = *(const short8*)(w3lo + aoff);
      }
#pragma unroll
      for (int nn = 0; nn < 2; nn++) {
        int boff = (nn * 16 + lr + (s >> 1)) * 72 + (s & 1) * 32 + lg2 * 8;
        Bh[nn] = *(const short8*)(act2p_hi + boff);
        Bl[nn] = *(const short8*)(act2p_lo + boff);
      }
#pragma unroll
      for (int mm = 0; mm < 2; mm++)
#pragma unroll
        for (int nn = 0; nn < 2; nn++) {
          acc[mm][nn] = __builtin_amdgcn_mfma_f32_16x16x32_bf16(Ah[mm], Bh[nn], acc[mm][nn], 0, 0, 0);
          acc[mm][nn] = __builtin_amdgcn_mfma_f32_16x16x32_bf16(Ah[mm], Bl[nn], acc[mm][nn], 0, 0, 0);
          acc[mm][nn] = __builtin_amdgcn_mfma_f32_16x16x32_bf16(Al[mm], Bh[nn], acc[mm][nn], 0, 0, 0);
        }
    }
#pragma unroll
    for (int mm = 0; mm < 2; mm++)
#pragma unroll
      for (int nn = 0; nn < 2; nn++) {
        int p = nn * 16 + lr;
        *(floatx4*)(act3t + p * 132 + (wv * 2 + mm) * 16 + lg2 * 4) = acc[mm][nn];
      }
  }
  __syncthreads();

  // ---- phase 6: pool4(first 24) + bias + relu + bn -> featsh (LDS) ----
  {
    int c = t & 127;
    float bb = b3[c], g = bn3g[c] * bnscale, be = bn3b[c];
    for (int pw = t >> 7; pw < 6; pw += 2) {
      int base = 4 * pw;
      float m = act3t[base * 132 + c];
      m = fmaxf(m, act3t[(base + 1) * 132 + c]);
      m = fmaxf(m, act3t[(base + 2) * 132 + c]);
      m = fmaxf(m, act3t[(base + 3) * 132 + c]);
      float v = fmaxf(m + bb, 0.f) * g + be;
      featsh[c * 6 + pw] = v;
    }
  }
  __syncthreads();

  // ---- phase 7: folded VQ scores + argmax -> proto_idx ----
  if (t < NPROTO * 8) {
    int p = t >> 3, part = t & 7;
    const float4* pr = reinterpret_cast<const float4*>(P3 + p * 768 + part * 96);
    const float4* fr = reinterpret_cast<const float4*>(featsh + part * 96);
    float4 a4 = make_float4(0.f, 0.f, 0.f, 0.f);
#pragma unroll
    for (int i = 0; i < 24; i++) {
      float4 w = pr[i], f = fr[i];
      a4.x += w.x * f.x; a4.y += w.y * f.y; a4.z += w.z * f.z; a4.w += w.w * f.w;
    }
    float a = (a4.x + a4.y) + (a4.z + a4.w);
    a += __shfl_xor(a, 1);
    a += __shfl_xor(a, 2);
    a += __shfl_xor(a, 4);
    if (part == 0) sc25[p] = a + c3[p];
  }
  __syncthreads();
  if (t == 0) {
    int best = 0; float bv = sc25[0];
    for (int i = 1; i < NPROTO; i++) {
      float v = sc25[i];
      if (v > bv) { bv = v; best = i; }
    }
    proto_idx[sample] = best;
  }
}

// ---------------- Kernel 3: sequence transformer + classifier ----------------
__global__ __launch_bounds__(512) void seq_kernel(
    const int* __restrict__ proto_idx, const float* __restrict__ protos,
    const float* __restrict__ inw, const float* __restrict__ inb,
    const float* __restrict__ outw, const float* __restrict__ outb,
    const float* __restrict__ ln1g, const float* __restrict__ ln1b,
    const float* __restrict__ ln2g, const float* __restrict__ ln2b,
    const float* __restrict__ ff1w, const float* __restrict__ ff1b,
    const float* __restrict__ ff2w, const float* __restrict__ ff2b,
    const float* __restrict__ clfw, const float* __restrict__ clfb,
    float* __restrict__ out) {
  __shared__ __align__(16) float hsh[SS * OUTD];
  __shared__ __align__(16) float big[SS * 3 * OUTD];
  __shared__ __align__(16) float sc[NHEAD * SS * SS];
  __shared__ __align__(16) float ctx[SS * OUTD];
  __shared__ float rowm[SS], rowv[SS];

  const int b = blockIdx.x;
  const int t = threadIdx.x;

  for (int o = t; o < SS * OUTD; o += 512) {
    int s = o >> 7, d = o & 127;
    int i0 = proto_idx[(b * SS + s) * 2];
    int i1 = proto_idx[(b * SS + s) * 2 + 1];
    float pc = 0.5f * (protos[i0 * OUTD + d] + protos[i1 * OUTD + d]);
    int i = d >> 1;
    float div = expf((float)(2 * i) * -0.07195578415606439f);
    float ang = (float)s * div;
    float pe = (d & 1) ? cosf(ang) : sinf(ang);
    hsh[o] = pc + pe;
  }
  __syncthreads();

  for (int o = t; o < SS * 384; o += 512) {
    int s = o / 384, j = o % 384;
    float4 a4 = make_float4(0.f, 0.f, 0.f, 0.f);
    const float4* hr = reinterpret_cast<const float4*>(&hsh[s * OUTD]);
    for (int d4 = 0; d4 < 32; d4++) {
      float4 h4 = hr[d4];
      int d = d4 * 4;
      a4.x += h4.x * inw[(d + 0) * 384 + j];
      a4.y += h4.y * inw[(d + 1) * 384 + j];
      a4.z += h4.z * inw[(d + 2) * 384 + j];
      a4.w += h4.w * inw[(d + 3) * 384 + j];
    }
    big[o] = inb[j] + ((a4.x + a4.y) + (a4.z + a4.w));
  }
  __syncthreads();

  for (int o = t; o < NHEAD * SS * SS; o += 512) {
    int hd = o / (SS * SS), r = o % (SS * SS), qs = r / SS, ks = r % SS;
    const float4* qp = reinterpret_cast<const float4*>(&big[qs * 384 + hd * 32]);
    const float4* kp = reinterpret_cast<const float4*>(&big[ks * 384 + 128 + hd * 32]);
    float4 a4 = make_float4(0.f, 0.f, 0.f, 0.f);
#pragma unroll
    for (int d4 = 0; d4 < 8; d4++) {
      float4 q4 = qp[d4], k4 = kp[d4];
      a4.x += q4.x * k4.x; a4.y += q4.y * k4.y; a4.z += q4.z * k4.z; a4.w += q4.w * k4.w;
    }
    sc[o] = ((a4.x + a4.y) + (a4.z + a4.w)) * 0.17677669529663689f;
  }
  __syncthreads();
  for (int r = t; r < NHEAD * SS; r += 512) {
    float* row = &sc[r * SS];
    float mx = row[0];
    for (int i = 1; i < SS; i++) mx = fmaxf(mx, row[i]);
    float sum = 0.f;
    for (int i = 0; i < SS; i++) { float e = expf(row[i] - mx); row[i] = e; sum += e; }
    float inv = 1.f / sum;
    for (int i = 0; i < SS; i++) row[i] *= inv;
  }
  __syncthreads();
  for (int o = t; o < SS * OUTD; o += 512) {
    int qs = o >> 7, d = o & 127, hd = d >> 5, dd = d & 31;
    const float* srow = &sc[(hd * SS + qs) * SS];
    float a = 0.f;
    for (int ks = 0; ks < SS; ks++) a += srow[ks] * big[ks * 384 + 256 + hd * 32 + dd];
    ctx[o] = a;
  }
  __syncthreads();
  float* tmp = big;
  for (int o = t; o < SS * OUTD; o += 512) {
    int s = o >> 7, d = o & 127;
    float4 a4 = make_float4(0.f, 0.f, 0.f, 0.f);
    const float4* cr = reinterpret_cast<const float4*>(&ctx[s * OUTD]);
    for (int e4 = 0; e4 < 32; e4++) {
      float4 c4 = cr[e4];
      int e = e4 * 4;
      a4.x += c4.x * outw[(e + 0) * OUTD + d];
      a4.y += c4.y * outw[(e + 1) * OUTD + d];
      a4.z += c4.z * outw[(e + 2) * OUTD + d];
      a4.w += c4.w * outw[(e + 3) * OUTD + d];
    }
    tmp[o] = hsh[o] + outb[d] + ((a4.x + a4.y) + (a4.z + a4.w));
  }
  __syncthreads();
  if (t < SS) {
    const float4* r4 = reinterpret_cast<const float4*>(&tmp[t * OUTD]);
    float4 m4 = make_float4(0.f, 0.f, 0.f, 0.f);
    for (int d4 = 0; d4 < 32; d4++) {
      float4 v = r4[d4];
      m4.x += v.x; m4.y += v.y; m4.z += v.z; m4.w += v.w;
    }
    float m = ((m4.x + m4.y) + (m4.z + m4.w)) * (1.0f / OUTD);
    float4 v4 = make_float4(0.f, 0.f, 0.f, 0.f);
    for (int d4 = 0; d4 < 32; d4++) {
      float4 v = r4[d4];
      float ux = v.x - m, uy = v.y - m, uz = v.z - m, uw = v.w - m;
      v4.x += ux * ux; v4.y += uy * uy; v4.z += uz * uz; v4.w += uw * uw;
    }
    float var = ((v4.x + v4.y) + (v4.z + v4.w)) * (1.0f / OUTD);
    rowm[t] = m; rowv[t] = rsqrtf(var + 1e-5f);
  }
  __syncthreads();
  for (int o = t; o < SS * OUTD; o += 512) {
    int s = o >> 7, d = o & 127;
    hsh[o] = (tmp[o] - rowm[s]) * rowv[s] * ln1g[d] + ln1b[d];
  }
  __syncthreads();
  for (int o = t; o < SS * OUTD; o += 512) {
    int s = o >> 7, d = o & 127;
    float4 a4 = make_float4(0.f, 0.f, 0.f, 0.f);
    const float4* hr = reinterpret_cast<const float4*>(&hsh[s * OUTD]);
    for (int e4 = 0; e4 < 32; e4++) {
      float4 h4 = hr[e4];
      int e = e4 * 4;
      a4.x += h4.x * ff1w[(e + 0) * OUTD + d];
      a4.y += h4.y * ff1w[(e + 1) * OUTD + d];
      a4.z += h4.z * ff1w[(e + 2) * OUTD + d];
      a4.w += h4.w * ff1w[(e + 3) * OUTD + d];
    }
    ctx[o] = fmaxf(ff1b[d] + ((a4.x + a4.y) + (a4.z + a4.w)), 0.f);
  }
  __syncthreads();
  for (int o = t; o < SS * OUTD; o += 512) {
    int s = o >> 7, d = o & 127;
    float4 a4 = make_float4(0.f, 0.f, 0.f, 0.f);
    const float4* cr = reinterpret_cast<const float4*>(&ctx[s * OUTD]);
    for (int e4 = 0; e4 < 32; e4++) {
      float4 c4 = cr[e4];
      int e = e4 * 4;
      a4.x += c4.x * ff2w[(e + 0) * OUTD + d];
      a4.y += c4.y * ff2w[(e + 1) * OUTD + d];
      a4.z += c4.z * ff2w[(e + 2) * OUTD + d];
      a4.w += c4.w * ff2w[(e + 3) * OUTD + d];
    }
    tmp[o] = hsh[o] + ff2b[d] + ((a4.x + a4.y) + (a4.z + a4.w));
  }
  __syncthreads();
  if (t < SS) {
    const float4* r4 = reinterpret_cast<const float4*>(&tmp[t * OUTD]);
    float4 m4 = make_float4(0.f, 0.f, 0.f, 0.f);
    for (int d4 = 0; d4 < 32; d4++) {
      float4 v = r4[d4];
      m4.x += v.x; m4.y += v.y; m4.z += v.z; m4.w += v.w;
    }
    float m = ((m4.x + m4.y) + (m4.z + m4.w)) * (1.0f / OUTD);
    float4 v4 = make_float4(0.f, 0.f, 0.f, 0.f);
    for (int d4 = 0; d4 < 32; d4++) {
      float4 v = r4[d4];
      float ux = v.x - m, uy = v.y - m, uz = v.z - m, uw = v.w - m;
      v4.x += ux * ux; v4.y += uy * uy; v4.z += uz * uz; v4.w += uw * uw;
    }
    float var = ((v4.x + v4.y) + (v4.z + v4.w)) * (1.0f / OUTD);
    rowm[t] = m; rowv[t] = rsqrtf(var + 1e-5f);
  }
  __syncthreads();
  for (int o = t; o < SS * OUTD; o += 512) {
    int s = o >> 7, d = o & 127;
    hsh[o] = (tmp[o] - rowm[s]) * rowv[s] * ln2g[d] + ln2b[d];
  }
  __syncthreads();
  for (int o = t; o < SS * NCLS; o += 512) {
    int s = o / NCLS, c = o % NCLS;
    float4 a4 = make_float4(0.f, 0.f, 0.f, 0.f);
    const float4* hr = reinterpret_cast<const float4*>(&hsh[s * OUTD]);
    for (int d4 = 0; d4 < 32; d4++) {
      float4 h4 = hr[d4];
      int d = d4 * 4;
      a4.x += h4.x * clfw[(d + 0) * NCLS + c];
      a4.y += h4.y * clfw[(d + 1) * NCLS + c];
      a4.z += h4.z * clfw[(d + 2) * NCLS + c];
      a4.w += h4.w * clfw[(d + 3) * NCLS + c];
    }
    out[(b * SS + s) * NCLS + c] = clfb[c] + ((a4.x + a4.y) + (a4.z + a4.w));
  }
}

extern "C" void kernel_launch(void* const* d_in, const int* in_sizes, int n_in,
                              void* d_out, int out_size, void* d_ws, size_t ws_size,
                              hipStream_t stream) {
  const float* x     = (const float*)d_in[0];
  const float* gum   = (const float*)d_in[1];
  const float* wq    = (const float*)d_in[2];
  const float* wk    = (const float*)d_in[3];
  const float* w1    = (const float*)d_in[4];
  const float* b1    = (const float*)d_in[5];
  const float* bn1g  = (const float*)d_in[6];
  const float* bn1b  = (const float*)d_in[7];
  const float* w2    = (const float*)d_in[8];
  const float* b2    = (const float*)d_in[9];
  const float* bn2g  = (const float*)d_in[10];
  const float* bn2b  = (const float*)d_in[11];
  const float* w3    = (const float*)d_in[12];
  const float* b3    = (const float*)d_in[13];
  const float* bn3g  = (const float*)d_in[14];
  const float* bn3b  = (const float*)d_in[15];
  const float* fcw   = (const float*)d_in[16];
  const float* fcb   = (const float*)d_in[17];
  const float* fc2w  = (const float*)d_in[18];
  const float* fc2b  = (const float*)d_in[19];
  const float* prot  = (const float*)d_in[20];
  const float* inw   = (const float*)d_in[21];
  const float* inb   = (const float*)d_in[22];
  const float* outw  = (const float*)d_in[23];
  const float* outb  = (const float*)d_in[24];
  const float* ln1g  = (const float*)d_in[25];
  const float* ln1b  = (const float*)d_in[26];
  const float* ln2g  = (const float*)d_in[27];
  const float* ln2b  = (const float*)d_in[28];
  const float* ff1w  = (const float*)d_in[29];
  const float* ff1b  = (const float*)d_in[30];
  const float* ff2w  = (const float*)d_in[31];
  const float* ff2b  = (const float*)d_in[32];
  const float* clfw  = (const float*)d_in[33];
  const float* clfb  = (const float*)d_in[34];
  float* out = (float*)d_out;

  int* sec_idx   = (int*)d_ws;
  int* proto_idx = sec_idx + NSAMPLE;
  short* w2hi = (short*)((float*)d_ws + WS_W2HI);
  short* w2lo = (short*)((float*)d_ws + WS_W2LO);
  short* w3hi = (short*)((float*)d_ws + WS_W3HI);
  short* w3lo = (short*)((float*)d_ws + WS_W3LO);
  float* P3 = (float*)d_ws + WS_P3;
  float* c3 = (float*)d_ws + WS_C3;

  hipLaunchKernelGGL(prep_kernel, dim3(120), dim3(256), 0, stream,
                     w2, w3, w2hi, w2lo, w3hi, w3lo);
  hipLaunchKernelGGL(prep2_kernel, dim3(NPROTO), dim3(256), 0, stream,
                     prot, fc2w, fcw, fcb, fc2b, P3, c3);
  hipLaunchKernelGGL(attn_kernel, dim3(BS / 4), dim3(512), 0, stream,
                     x, gum, wq, wk, sec_idx);
  hipLaunchKernelGGL(conv_kernel, dim3(NSAMPLE), dim3(256), 0, stream,
                     x, sec_idx, w1, b1, bn1g, bn1b, w2hi, w2lo, b2, bn2g, bn2b,
                     w3hi, w3lo, b3, bn3g, bn3b, P3, c3, proto_idx);
  hipLaunchKernelGGL(seq_kernel, dim3(BB), dim3(512), 0, stream,
                     proto_idx, prot, inw, inb, outw, outb,
                     ln1g, ln1b, ln2g, ln2b, ff1w, ff1b, ff2w, ff2b,
                     clfw, clfb, out);
}

// Round 5
// 252.033 us; speedup vs baseline: 3.4943x; 1.0010x over previous
//
#include <hip/hip_runtime.h>
#include <math.h>

#define BB 64
#define SS 21
#define NSAMP 3000
#define HID 500
#define SECN 6
#define NN 2
#define OUTD 128
#define NPROTO 25
#define NCLS 5
#define NHEAD 4
#define BS (BB*SS)          // 1344
#define NSAMPLE (BS*NN)     // 2688

#define C500 (-0.0184206807439523674f)   // -ln(1e4)/500
#define LSCALE 0.00745355992499929898f   // 1/(6*sqrt(500))

// ws float offsets
#define WS_W2HI 5376
#define WS_W2LO 8448
#define WS_W3HI 11520
#define WS_W3LO 23808
#define WS_P3   36096
#define WS_C3   55296
#define WS_XSUM 55424
#define WS_V    727424

typedef __attribute__((ext_vector_type(8))) short short8;
typedef __attribute__((ext_vector_type(4))) float floatx4;

__device__ __forceinline__ short f2bf(float f) {
  unsigned u = __float_as_uint(f);
  u += 0x7FFF + ((u >> 16) & 1);          // RNE to bf16
  return (short)(u >> 16);
}
__device__ __forceinline__ float bf2f(short h) {
  return __uint_as_float(((unsigned)(unsigned short)h) << 16);
}

// ---------------- Kernel 0: weight splits + folded-VQ prep (merged) ----------------
__global__ __launch_bounds__(256) void prep_all_kernel(
    const float* __restrict__ w2, const float* __restrict__ w3,
    short* __restrict__ w2hi, short* __restrict__ w2lo,
    short* __restrict__ w3hi, short* __restrict__ w3lo,
    const float* __restrict__ protos, const float* __restrict__ fc2w,
    const float* __restrict__ fcw, const float* __restrict__ fcb,
    const float* __restrict__ fc2b,
    float* __restrict__ P3, float* __restrict__ c3) {
  __shared__ __align__(16) float p2row[256];
  __shared__ float red[256];
  if (blockIdx.x < 120) {
    int idx = blockIdx.x * 256 + threadIdx.x;
    if (idx < 6144) {
      int ic = idx & 31, ck = idx >> 5, k = ck % 3, c = ck / 3;
      float v = w2[c * 96 + ic * 3 + k];
      int dst = c * 96 + k * 32 + ic;
      short hi = f2bf(v);
      short lo = f2bf(v - bf2f(hi));
      w2hi[dst] = hi; w2lo[dst] = lo;
    } else if (idx < 30720) {
      int j = idx - 6144;
      int ic = j & 63, ck = j >> 6, k = ck % 3, c = ck / 3;
      float v = w3[(c * 64 + ic) * 3 + k];
      int dst = c * 192 + k * 64 + ic;
      short hi = f2bf(v);
      short lo = f2bf(v - bf2f(hi));
      w3hi[dst] = hi; w3lo[dst] = lo;
    }
    return;
  }
  const int p = blockIdx.x - 120, j = threadIdx.x;
  {
    const float4* pr = reinterpret_cast<const float4*>(protos + p * 128);
    const float4* wr = reinterpret_cast<const float4*>(fc2w + j * 128);
    float4 a4 = make_float4(0.f, 0.f, 0.f, 0.f);
    for (int c4 = 0; c4 < 32; c4++) {
      float4 a = pr[c4], b = wr[c4];
      a4.x += a.x * b.x; a4.y += a.y * b.y; a4.z += a.z * b.z; a4.w += a.w * b.w;
    }
    float v = (a4.x + a4.y) + (a4.z + a4.w);
    p2row[j] = v;
    float contrib = v * fcb[j];
    if (j < 128) {
      float pv = protos[p * 128 + j];
      contrib += pv * fc2b[j] - 0.5f * pv * pv;
    }
    red[j] = contrib;
  }
  __syncthreads();
  for (int s = 128; s > 0; s >>= 1) {
    if (j < s) red[j] += red[j + s];
    __syncthreads();
  }
  if (j == 0) c3[p] = red[0];
  for (int k = j; k < 768; k += 256) {
    const float4* fr = reinterpret_cast<const float4*>(fcw + k * 256);
    const float4* p2 = reinterpret_cast<const float4*>(p2row);
    float4 a4 = make_float4(0.f, 0.f, 0.f, 0.f);
    for (int j4 = 0; j4 < 64; j4++) {
      float4 a = p2[j4], b = fr[j4];
      a4.x += a.x * b.x; a4.y += a.y * b.y; a4.z += a.z * b.z; a4.w += a.w * b.w;
    }
    P3[p * 768 + k] = (a4.x + a4.y) + (a4.z + a4.w);
  }
}

// ---------------- Kernel 1a: xsum[bs][500] = sum_s x + PE-sum ----------------
__global__ __launch_bounds__(128) void attn_a_kernel(
    const float* __restrict__ x, float* __restrict__ xsum) {
  const int bs = blockIdx.x, t = threadIdx.x;
  if (t >= 125) return;
  const float4* x4 = reinterpret_cast<const float4*>(x) + bs * 750;
  float4 a = x4[t];
#pragma unroll
  for (int s = 1; s < SECN; s++) {
    float4 b = x4[s * 125 + t];
    a.x += b.x; a.y += b.y; a.z += b.z; a.w += b.w;
  }
  float div0 = expf((float)(4 * t) * C500);
  float div1 = expf((float)(4 * t + 2) * C500);
  float s0 = 0.f, c0 = 0.f, s1 = 0.f, c1 = 0.f;
#pragma unroll
  for (int s = 0; s < SECN; s++) {
    float a0 = (float)s * div0, a1 = (float)s * div1;
    s0 += sinf(a0); c0 += cosf(a0);
    s1 += sinf(a1); c1 += cosf(a1);
  }
  a.x += s0; a.y += c0; a.z += s1; a.w += c1;
  reinterpret_cast<float4*>(xsum)[bs * 125 + t] = a;
}

// ---------------- Kernel 1b: ks = xsum@wk ; v[bs][n][500] = wq_n@ks_n ----------------
#define MB 8
__global__ __launch_bounds__(256) void attn_b_kernel(
    const float* __restrict__ xsum, const float* __restrict__ wk,
    const float* __restrict__ wq, float* __restrict__ v) {
  __shared__ __align__(16) float xs[MB * 500];
  __shared__ __align__(16) float kssh[MB * 256];
  const int blk = blockIdx.x, t = threadIdx.x;

  for (int e = t; e < MB * 125; e += 256)
    reinterpret_cast<float4*>(xs)[e] =
        reinterpret_cast<const float4*>(xsum)[blk * MB * 125 + e];
  __syncthreads();

  {
    float acc[MB];
#pragma unroll
    for (int m = 0; m < MB; m++) acc[m] = 0.f;
#pragma unroll 4
    for (int i = 0; i < 500; i++) {
      float w = wk[i * 256 + t];
#pragma unroll
      for (int m = 0; m < MB; m++) acc[m] += xs[m * 500 + i] * w;
    }
#pragma unroll
    for (int m = 0; m < MB; m++) kssh[m * 256 + t] = acc[m];
  }
  __syncthreads();

  for (int h = t; h < 500; h += 256) {
#pragma unroll
    for (int n = 0; n < 2; n++) {
      const float4* wqr = reinterpret_cast<const float4*>(wq + h * 256 + n * 128);
      const float4* ksb = reinterpret_cast<const float4*>(kssh + n * 128);
      float acc[MB];
#pragma unroll
      for (int m = 0; m < MB; m++) acc[m] = 0.f;
      for (int c4 = 0; c4 < 32; c4++) {
        float4 w4 = wqr[c4];
#pragma unroll
        for (int m = 0; m < MB; m++) {
          float4 k4 = ksb[m * 64 + c4];
          acc[m] += w4.x * k4.x + w4.y * k4.y + w4.z * k4.z + w4.w * k4.w;
        }
      }
#pragma unroll
      for (int m = 0; m < MB; m++)
        v[((blk * MB + m) * 2 + n) * 500 + h] = acc[m];
    }
  }
}

// ---------------- Kernel 1c: logits = (x+pe).v + gumbel -> argmax ----------------
__global__ __launch_bounds__(192) void attn_c_kernel(
    const float* __restrict__ x, const float* __restrict__ v,
    const float* __restrict__ gumbel, int* __restrict__ sec_idx) {
  __shared__ float lgsh[NN][SECN];
  const int bs = blockIdx.x, t = threadIdx.x;
  const int s = t >> 5, lane = t & 31;
  const float4* x4 = reinterpret_cast<const float4*>(x) + bs * 750 + s * 125;
  const float4* v0 = reinterpret_cast<const float4*>(v) + bs * 250;
  const float4* v1 = v0 + 125;
  float a0 = 0.f, a1 = 0.f;
  for (int h4 = lane; h4 < 125; h4 += 32) {
    float4 xv = x4[h4];
    float div0 = expf((float)(4 * h4) * C500);
    float div1 = expf((float)(4 * h4 + 2) * C500);
    float ang0 = (float)s * div0, ang1 = (float)s * div1;
    xv.x += sinf(ang0); xv.y += cosf(ang0);
    xv.z += sinf(ang1); xv.w += cosf(ang1);
    float4 w0 = v0[h4], w1 = v1[h4];
    a0 += xv.x * w0.x + xv.y * w0.y + xv.z * w0.z + xv.w * w0.w;
    a1 += xv.x * w1.x + xv.y * w1.y + xv.z * w1.z + xv.w * w1.w;
  }
#pragma unroll
  for (int m = 16; m >= 1; m >>= 1) {
    a0 += __shfl_xor(a0, m);
    a1 += __shfl_xor(a1, m);
  }
  if (lane == 0) {
    lgsh[0][s] = a0 * LSCALE + gumbel[(bs * 2 + 0) * SECN + s];
    lgsh[1][s] = a1 * LSCALE + gumbel[(bs * 2 + 1) * SECN + s];
  }
  __syncthreads();
  if (t < 2) {
    int best = 0; float bv = lgsh[t][0];
    for (int i = 1; i < SECN; i++) {
      float q = lgsh[t][i];
      if (q > bv) { bv = q; best = i; }
    }
    sec_idx[bs * 2 + t] = best;
  }
}

// ---------------- Kernel 2: conv encoder (MFMA) + folded VQ argmax ----------------
// LDS: [0,20800) act1 hi/lo -> act2p hi/lo + featsh/sc25 alias
//      [20800, 53568) in0p -> act2t[128][64] (XOR-swizzled) -> act3t[32][132]
#define CONV_LDS 53568
__global__ __launch_bounds__(256, 3) void conv_kernel(
    const float* __restrict__ x, const int* __restrict__ sec_idx,
    const float* __restrict__ w1, const float* __restrict__ b1,
    const float* __restrict__ bn1g, const float* __restrict__ bn1b,
    const short* __restrict__ w2hi, const short* __restrict__ w2lo,
    const float* __restrict__ b2,
    const float* __restrict__ bn2g, const float* __restrict__ bn2b,
    const short* __restrict__ w3hi, const short* __restrict__ w3lo,
    const float* __restrict__ b3,
    const float* __restrict__ bn3g, const float* __restrict__ bn3b,
    const float* __restrict__ P3, const float* __restrict__ c3,
    int* __restrict__ proto_idx) {
  __shared__ __align__(16) char smem[CONV_LDS];
  short* act1_hi  = (short*)smem;               // [130][40]
  short* act1_lo  = (short*)(smem + 10400);     // [130][40]
  short* act2p_hi = (short*)smem;               // [34][72]
  short* act2p_lo = (short*)(smem + 4896);      // [34][72]
  float* featsh   = (float*)(smem + 9792);      // [768] (alias, phases 6-7)
  float* sc25     = (float*)(smem + 12864);     // [25]
  float* in0p  = (float*)(smem + 20800);        // [512]
  float* act2t = (float*)(smem + 20800);        // [128][64] swizzled
  float* act3t = (float*)(smem + 20800);        // [32][132]

  const int sample = blockIdx.x;
  const int t = threadIdx.x;
  const int bsIdx = sample >> 1;
  const float bnscale = rsqrtf(1.0f + 1e-5f);
  const int wv = t >> 6, l = t & 63, lr = l & 15, lg2 = l >> 4;

  // ---- phase 1: load x section (padded), zero act1 pad rows ----
  {
    int sec = sec_idx[sample];
    const float* src = &x[bsIdx * NSAMP + sec * HID];
    for (int i = t; i < 512; i += 256) in0p[i] = (i >= 1 && i <= 500) ? src[i - 1] : 0.f;
    if (t < 200) {
      int r = t / 40; r = (r == 0) ? 0 : 125 + r;   // rows 0,126..129
      int idx = r * 40 + t % 40;
      act1_hi[idx] = 0; act1_lo[idx] = 0;
    }
  }
  __syncthreads();

  // ---- phase 2: conv1 + relu + pool4 + bn -> act1 hi/lo bf16 [pos+1][ic] ----
  {
    int ic = t & 31;
    float w0 = w1[ic * 3], w1v = w1[ic * 3 + 1], w2v = w1[ic * 3 + 2];
    float bb = b1[ic];
    float g = bn1g[ic] * bnscale, be = bn1b[ic];
    for (int p = t >> 5; p < 125; p += 8) {
      int base = 4 * p;
      float xm1 = in0p[base], x0 = in0p[base + 1], x1 = in0p[base + 2],
            x2 = in0p[base + 3], x3 = in0p[base + 4], x4 = in0p[base + 5];
      float a0 = bb + w0 * xm1 + w1v * x0 + w2v * x1;
      float a1 = bb + w0 * x0  + w1v * x1 + w2v * x2;
      float a2 = bb + w0 * x1  + w1v * x2 + w2v * x3;
      float a3 = bb + w0 * x2  + w1v * x3 + w2v * x4;
      float m = fmaxf(fmaxf(fmaxf(fmaxf(a0, a1), a2), a3), 0.f);
      float v = m * g + be;
      short hi = f2bf(v);
      short lo = f2bf(v - bf2f(hi));
      act1_hi[(p + 1) * 40 + ic] = hi;
      act1_lo[(p + 1) * 40 + ic] = lo;
    }
  }
  __syncthreads();

  // ---- phase 3: conv2 MFMA  C[64ch][128pos] = W2[64][96] @ B2 ----
  {
    floatx4 acc[4][2];
#pragma unroll
    for (int m = 0; m < 4; m++)
#pragma unroll
      for (int nn = 0; nn < 2; nn++) acc[m][nn] = (floatx4){0.f, 0.f, 0.f, 0.f};
#pragma unroll
    for (int s = 0; s < 3; s++) {
      short8 Ah[4], Al[4], Bh[2], Bl[2];
#pragma unroll
      for (int m = 0; m < 4; m++) {
        int aoff = (m * 16 + lr) * 96 + s * 32 + lg2 * 8;
        Ah[m] = *(const short8*)(w2hi + aoff);
        Al[m] = *(const short8*)(w2lo + aoff);
      }
#pragma unroll
      for (int nn = 0; nn < 2; nn++) {
        int boff = ((2 * wv + nn) * 16 + lr + s) * 40 + lg2 * 8;
        Bh[nn] = *(const short8*)(act1_hi + boff);
        Bl[nn] = *(const short8*)(act1_lo + boff);
      }
#pragma unroll
      for (int m = 0; m < 4; m++)
#pragma unroll
        for (int nn = 0; nn < 2; nn++) {
          acc[m][nn] = __builtin_amdgcn_mfma_f32_16x16x32_bf16(Ah[m], Bh[nn], acc[m][nn], 0, 0, 0);
          acc[m][nn] = __builtin_amdgcn_mfma_f32_16x16x32_bf16(Ah[m], Bl[nn], acc[m][nn], 0, 0, 0);
          acc[m][nn] = __builtin_amdgcn_mfma_f32_16x16x32_bf16(Al[m], Bh[nn], acc[m][nn], 0, 0, 0);
        }
    }
    // swizzled store: element (pos p, ch m*16+lg2*4+j) at p*64 + ((m*4+lg2)^(p&15))*4 + j
#pragma unroll
    for (int m = 0; m < 4; m++)
#pragma unroll
      for (int nn = 0; nn < 2; nn++) {
        int p = (2 * wv + nn) * 16 + lr;
        int swz = (m * 4 + lg2) ^ lr;    // p&15 == lr
        *(floatx4*)(act2t + p * 64 + swz * 4) = acc[m][nn];
      }
  }
  __syncthreads();

  // ---- phase 4: pool5 + bias + relu + bn -> act2p hi/lo; zero pads ----
  {
    if (t < 162) {
      for (int i = t; i < 648; i += 162) {
        int r = i / 72; r = (r == 0) ? 0 : 25 + r;
        int idx = r * 72 + i % 72;
        act2p_hi[idx] = 0; act2p_lo[idx] = 0;
      }
    }
    int ic = t & 63;
    float bb = b2[ic], g = bn2g[ic] * bnscale, be = bn2b[ic];
#define A2T(r, c) act2t[(r) * 64 + ((((c) >> 2) ^ ((r) & 15)) << 2) + ((c) & 3)]
    for (int pw = t >> 6; pw < 25; pw += 4) {
      int base = 5 * pw;
      float m = A2T(base, ic);
      m = fmaxf(m, A2T(base + 1, ic));
      m = fmaxf(m, A2T(base + 2, ic));
      m = fmaxf(m, A2T(base + 3, ic));
      m = fmaxf(m, A2T(base + 4, ic));
      float v = fmaxf(m + bb, 0.f) * g + be;
      short hi = f2bf(v);
      short lo = f2bf(v - bf2f(hi));
      act2p_hi[(pw + 1) * 72 + ic] = hi;
      act2p_lo[(pw + 1) * 72 + ic] = lo;
    }
#undef A2T
  }
  __syncthreads();

  // ---- phase 5: conv3 MFMA  C[128ch][32pos] = W3[128][192] @ B3 ----
  {
    floatx4 acc[2][2];
#pragma unroll
    for (int mm = 0; mm < 2; mm++)
#pragma unroll
      for (int nn = 0; nn < 2; nn++) acc[mm][nn] = (floatx4){0.f, 0.f, 0.f, 0.f};
#pragma unroll
    for (int s = 0; s < 6; s++) {
      short8 Ah[2], Al[2], Bh[2], Bl[2];
#pragma unroll
      for (int mm = 0; mm < 2; mm++) {
        int aoff = ((wv * 2 + mm) * 16 + lr) * 192 + s * 32 + lg2 * 8;
        Ah[mm] = *(const short8*)(w3hi + aoff);
        Al[mm] = *(const short8*)(w3lo + aoff);
      }
#pragma unroll
      for (int nn = 0; nn < 2; nn++) {
        int boff = (nn * 16 + lr + (s >> 1)) * 72 + (s & 1) * 32 + lg2 * 8;
        Bh[nn] = *(const short8*)(act2p_hi + boff);
        Bl[nn] = *(const short8*)(act2p_lo + boff);
      }
#pragma unroll
      for (int mm = 0; mm < 2; mm++)
#pragma unroll
        for (int nn = 0; nn < 2; nn++) {
          acc[mm][nn] = __builtin_amdgcn_mfma_f32_16x16x32_bf16(Ah[mm], Bh[nn], acc[mm][nn], 0, 0, 0);
          acc[mm][nn] = __builtin_amdgcn_mfma_f32_16x16x32_bf16(Ah[mm], Bl[nn], acc[mm][nn], 0, 0, 0);
          acc[mm][nn] = __builtin_amdgcn_mfma_f32_16x16x32_bf16(Al[mm], Bh[nn], acc[mm][nn], 0, 0, 0);
        }
    }
#pragma unroll
    for (int mm = 0; mm < 2; mm++)
#pragma unroll
      for (int nn = 0; nn < 2; nn++) {
        int p = nn * 16 + lr;
        *(floatx4*)(act3t + p * 132 + (wv * 2 + mm) * 16 + lg2 * 4) = acc[mm][nn];
      }
  }
  __syncthreads();

  // ---- phase 6: pool4(first 24) + bias + relu + bn -> featsh (LDS) ----
  {
    int c = t & 127;
    float bb = b3[c], g = bn3g[c] * bnscale, be = bn3b[c];
    for (int pw = t >> 7; pw < 6; pw += 2) {
      int base = 4 * pw;
      float m = act3t[base * 132 + c];
      m = fmaxf(m, act3t[(base + 1) * 132 + c]);
      m = fmaxf(m, act3t[(base + 2) * 132 + c]);
      m = fmaxf(m, act3t[(base + 3) * 132 + c]);
      float v = fmaxf(m + bb, 0.f) * g + be;
      featsh[c * 6 + pw] = v;
    }
  }
  __syncthreads();

  // ---- phase 7: folded VQ scores + argmax -> proto_idx ----
  if (t < NPROTO * 8) {
    int p = t >> 3, part = t & 7;
    const float4* pr = reinterpret_cast<const float4*>(P3 + p * 768 + part * 96);
    const float4* fr = reinterpret_cast<const float4*>(featsh + part * 96);
    float4 a4 = make_float4(0.f, 0.f, 0.f, 0.f);
#pragma unroll
    for (int i = 0; i < 24; i++) {
      float4 w = pr[i], f = fr[i];
      a4.x += w.x * f.x; a4.y += w.y * f.y; a4.z += w.z * f.z; a4.w += w.w * f.w;
    }
    float a = (a4.x + a4.y) + (a4.z + a4.w);
    a += __shfl_xor(a, 1);
    a += __shfl_xor(a, 2);
    a += __shfl_xor(a, 4);
    if (part == 0) sc25[p] = a + c3[p];
  }
  __syncthreads();
  if (t == 0) {
    int best = 0; float bv = sc25[0];
    for (int i = 1; i < NPROTO; i++) {
      float v = sc25[i];
      if (v > bv) { bv = v; best = i; }
    }
    proto_idx[sample] = best;
  }
}

// ---------------- Kernel 3: sequence transformer + classifier ----------------
__global__ __launch_bounds__(512) void seq_kernel(
    const int* __restrict__ proto_idx, const float* __restrict__ protos,
    const float* __restrict__ inw, const float* __restrict__ inb,
    const float* __restrict__ outw, const float* __restrict__ outb,
    const float* __restrict__ ln1g, const float* __restrict__ ln1b,
    const float* __restrict__ ln2g, const float* __restrict__ ln2b,
    const float* __restrict__ ff1w, const float* __restrict__ ff1b,
    const float* __restrict__ ff2w, const float* __restrict__ ff2b,
    const float* __restrict__ clfw, const float* __restrict__ clfb,
    float* __restrict__ out) {
  __shared__ __align__(16) float hsh[SS * OUTD];
  __shared__ __align__(16) float big[SS * 3 * OUTD];
  __shared__ __align__(16) float sc[NHEAD * SS * SS];
  __shared__ __align__(16) float ctx[SS * OUTD];
  __shared__ float rowm[SS], rowv[SS];

  const int b = blockIdx.x;
  const int t = threadIdx.x;

  for (int o = t; o < SS * OUTD; o += 512) {
    int s = o >> 7, d = o & 127;
    int i0 = proto_idx[(b * SS + s) * 2];
    int i1 = proto_idx[(b * SS + s) * 2 + 1];
    float pc = 0.5f * (protos[i0 * OUTD + d] + protos[i1 * OUTD + d]);
    int i = d >> 1;
    float div = expf((float)(2 * i) * -0.07195578415606439f);
    float ang = (float)s * div;
    float pe = (d & 1) ? cosf(ang) : sinf(ang);
    hsh[o] = pc + pe;
  }
  __syncthreads();

  for (int o = t; o < SS * 384; o += 512) {
    int s = o / 384, j = o % 384;
    float4 a4 = make_float4(0.f, 0.f, 0.f, 0.f);
    const float4* hr = reinterpret_cast<const float4*>(&hsh[s * OUTD]);
    for (int d4 = 0; d4 < 32; d4++) {
      float4 h4 = hr[d4];
      int d = d4 * 4;
      a4.x += h4.x * inw[(d + 0) * 384 + j];
      a4.y += h4.y * inw[(d + 1) * 384 + j];
      a4.z += h4.z * inw[(d + 2) * 384 + j];
      a4.w += h4.w * inw[(d + 3) * 384 + j];
    }
    big[o] = inb[j] + ((a4.x + a4.y) + (a4.z + a4.w));
  }
  __syncthreads();

  for (int o = t; o < NHEAD * SS * SS; o += 512) {
    int hd = o / (SS * SS), r = o % (SS * SS), qs = r / SS, ks = r % SS;
    const float4* qp = reinterpret_cast<const float4*>(&big[qs * 384 + hd * 32]);
    const float4* kp = reinterpret_cast<const float4*>(&big[ks * 384 + 128 + hd * 32]);
    float4 a4 = make_float4(0.f, 0.f, 0.f, 0.f);
#pragma unroll
    for (int d4 = 0; d4 < 8; d4++) {
      float4 q4 = qp[d4], k4 = kp[d4];
      a4.x += q4.x * k4.x; a4.y += q4.y * k4.y; a4.z += q4.z * k4.z; a4.w += q4.w * k4.w;
    }
    sc[o] = ((a4.x + a4.y) + (a4.z + a4.w)) * 0.17677669529663689f;
  }
  __syncthreads();
  for (int r = t; r < NHEAD * SS; r += 512) {
    float* row = &sc[r * SS];
    float mx = row[0];
    for (int i = 1; i < SS; i++) mx = fmaxf(mx, row[i]);
    float sum = 0.f;
    for (int i = 0; i < SS; i++) { float e = expf(row[i] - mx); row[i] = e; sum += e; }
    float inv = 1.f / sum;
    for (int i = 0; i < SS; i++) row[i] *= inv;
  }
  __syncthreads();
  for (int o = t; o < SS * OUTD; o += 512) {
    int qs = o >> 7, d = o & 127, hd = d >> 5, dd = d & 31;
    const float* srow = &sc[(hd * SS + qs) * SS];
    float a = 0.f;
    for (int ks = 0; ks < SS; ks++) a += srow[ks] * big[ks * 384 + 256 + hd * 32 + dd];
    ctx[o] = a;
  }
  __syncthreads();
  float* tmp = big;
  for (int o = t; o < SS * OUTD; o += 512) {
    int s = o >> 7, d = o & 127;
    float4 a4 = make_float4(0.f, 0.f, 0.f, 0.f);
    const float4* cr = reinterpret_cast<const float4*>(&ctx[s * OUTD]);
    for (int e4 = 0; e4 < 32; e4++) {
      float4 c4 = cr[e4];
      int e = e4 * 4;
      a4.x += c4.x * outw[(e + 0) * OUTD + d];
      a4.y += c4.y * outw[(e + 1) * OUTD + d];
      a4.z += c4.z * outw[(e + 2) * OUTD + d];
      a4.w += c4.w * outw[(e + 3) * OUTD + d];
    }
    tmp[o] = hsh[o] + outb[d] + ((a4.x + a4.y) + (a4.z + a4.w));
  }
  __syncthreads();
  if (t < SS) {
    const float4* r4 = reinterpret_cast<const float4*>(&tmp[t * OUTD]);
    float4 m4 = make_float4(0.f, 0.f, 0.f, 0.f);
    for (int d4 = 0; d4 < 32; d4++) {
      float4 v = r4[d4];
      m4.x += v.x; m4.y += v.y; m4.z += v.z; m4.w += v.w;
    }
    float m = ((m4.x + m4.y) + (m4.z + m4.w)) * (1.0f / OUTD);
    float4 v4 = make_float4(0.f, 0.f, 0.f, 0.f);
    for (int d4 = 0; d4 < 32; d4++) {
      float4 v = r4[d4];
      float ux = v.x - m, uy = v.y - m, uz = v.z - m, uw = v.w - m;
      v4.x += ux * ux; v4.y += uy * uy; v4.z += uz * uz; v4.w += uw * uw;
    }
    float var = ((v4.x + v4.y) + (v4.z + v4.w)) * (1.0f / OUTD);
    rowm[t] = m; rowv[t] = rsqrtf(var + 1e-5f);
  }
  __syncthreads();
  for (int o = t; o < SS * OUTD; o += 512) {
    int s = o >> 7, d = o & 127;
    hsh[o] = (tmp[o] - rowm[s]) * rowv[s] * ln1g[d] + ln1b[d];
  }
  __syncthreads();
  for (int o = t; o < SS * OUTD; o += 512) {
    int s = o >> 7, d = o & 127;
    float4 a4 = make_float4(0.f, 0.f, 0.f, 0.f);
    const float4* hr = reinterpret_cast<const float4*>(&hsh[s * OUTD]);
    for (int e4 = 0; e4 < 32; e4++) {
      float4 h4 = hr[e4];
      int e = e4 * 4;
      a4.x += h4.x * ff1w[(e + 0) * OUTD + d];
      a4.y += h4.y * ff1w[(e + 1) * OUTD + d];
      a4.z += h4.z * ff1w[(e + 2) * OUTD + d];
      a4.w += h4.w * ff1w[(e + 3) * OUTD + d];
    }
    ctx[o] = fmaxf(ff1b[d] + ((a4.x + a4.y) + (a4.z + a4.w)), 0.f);
  }
  __syncthreads();
  for (int o = t; o < SS * OUTD; o += 512) {
    int s = o >> 7, d = o & 127;
    float4 a4 = make_float4(0.f, 0.f, 0.f, 0.f);
    const float4* cr = reinterpret_cast<const float4*>(&ctx[s * OUTD]);
    for (int e4 = 0; e4 < 32; e4++) {
      float4 c4 = cr[e4];
      int e = e4 * 4;
      a4.x += c4.x * ff2w[(e + 0) * OUTD + d];
      a4.y += c4.y * ff2w[(e + 1) * OUTD + d];
      a4.z += c4.z * ff2w[(e + 2) * OUTD + d];
      a4.w += c4.w * ff2w[(e + 3) * OUTD + d];
    }
    tmp[o] = hsh[o] + ff2b[d] + ((a4.x + a4.y) + (a4.z + a4.w));
  }
  __syncthreads();
  if (t < SS) {
    const float4* r4 = reinterpret_cast<const float4*>(&tmp[t * OUTD]);
    float4 m4 = make_float4(0.f, 0.f, 0.f, 0.f);
    for (int d4 = 0; d4 < 32; d4++) {
      float4 v = r4[d4];
      m4.x += v.x; m4.y += v.y; m4.z += v.z; m4.w += v.w;
    }
    float m = ((m4.x + m4.y) + (m4.z + m4.w)) * (1.0f / OUTD);
    float4 v4 = make_float4(0.f, 0.f, 0.f, 0.f);
    for (int d4 = 0; d4 < 32; d4++) {
      float4 v = r4[d4];
      float ux = v.x - m, uy = v.y - m, uz = v.z - m, uw = v.w - m;
      v4.x += ux * ux; v4.y += uy * uy; v4.z += uz * uz; v4.w += uw * uw;
    }
    float var = ((v4.x + v4.y) + (v4.z + v4.w)) * (1.0f / OUTD);
    rowm[t] = m; rowv[t] = rsqrtf(var + 1e-5f);
  }
  __syncthreads();
  for (int o = t; o < SS * OUTD; o += 512) {
    int s = o >> 7, d = o & 127;
    hsh[o] = (tmp[o] - rowm[s]) * rowv[s] * ln2g[d] + ln2b[d];
  }
  __syncthreads();
  for (int o = t; o < SS * NCLS; o += 512) {
    int s = o / NCLS, c = o % NCLS;
    float4 a4 = make_float4(0.f, 0.f, 0.f, 0.f);
    const float4* hr = reinterpret_cast<const float4*>(&hsh[s * OUTD]);
    for (int d4 = 0; d4 < 32; d4++) {
      float4 h4 = hr[d4];
      int d = d4 * 4;
      a4.x += h4.x * clfw[(d + 0) * NCLS + c];
      a4.y += h4.y * clfw[(d + 1) * NCLS + c];
      a4.z += h4.z * clfw[(d + 2) * NCLS + c];
      a4.w += h4.w * clfw[(d + 3) * NCLS + c];
    }
    out[(b * SS + s) * NCLS + c] = clfb[c] + ((a4.x + a4.y) + (a4.z + a4.w));
  }
}

extern "C" void kernel_launch(void* const* d_in, const int* in_sizes, int n_in,
                              void* d_out, int out_size, void* d_ws, size_t ws_size,
                              hipStream_t stream) {
  const float* x     = (const float*)d_in[0];
  const float* gum   = (const float*)d_in[1];
  const float* wq    = (const float*)d_in[2];
  const float* wk    = (const float*)d_in[3];
  const float* w1    = (const float*)d_in[4];
  const float* b1    = (const float*)d_in[5];
  const float* bn1g  = (const float*)d_in[6];
  const float* bn1b  = (const float*)d_in[7];
  const float* w2    = (const float*)d_in[8];
  const float* b2    = (const float*)d_in[9];
  const float* bn2g  = (const float*)d_in[10];
  const float* bn2b  = (const float*)d_in[11];
  const float* w3    = (const float*)d_in[12];
  const float* b3    = (const float*)d_in[13];
  const float* bn3g  = (const float*)d_in[14];
  const float* bn3b  = (const float*)d_in[15];
  const float* fcw   = (const float*)d_in[16];
  const float* fcb   = (const float*)d_in[17];
  const float* fc2w  = (const float*)d_in[18];
  const float* fc2b  = (const float*)d_in[19];
  const float* prot  = (const float*)d_in[20];
  const float* inw   = (const float*)d_in[21];
  const float* inb   = (const float*)d_in[22];
  const float* outw  = (const float*)d_in[23];
  const float* outb  = (const float*)d_in[24];
  const float* ln1g  = (const float*)d_in[25];
  const float* ln1b  = (const float*)d_in[26];
  const float* ln2g  = (const float*)d_in[27];
  const float* ln2b  = (const float*)d_in[28];
  const float* ff1w  = (const float*)d_in[29];
  const float* ff1b  = (const float*)d_in[30];
  const float* ff2w  = (const float*)d_in[31];
  const float* ff2b  = (const float*)d_in[32];
  const float* clfw  = (const float*)d_in[33];
  const float* clfb  = (const float*)d_in[34];
  float* out = (float*)d_out;

  int* sec_idx   = (int*)d_ws;
  int* proto_idx = sec_idx + NSAMPLE;
  short* w2hi = (short*)((float*)d_ws + WS_W2HI);
  short* w2lo = (short*)((float*)d_ws + WS_W2LO);
  short* w3hi = (short*)((float*)d_ws + WS_W3HI);
  short* w3lo = (short*)((float*)d_ws + WS_W3LO);
  float* P3   = (float*)d_ws + WS_P3;
  float* c3   = (float*)d_ws + WS_C3;
  float* xsum = (float*)d_ws + WS_XSUM;
  float* vbuf = (float*)d_ws + WS_V;

  hipLaunchKernelGGL(prep_all_kernel, dim3(145), dim3(256), 0, stream,
                     w2, w3, w2hi, w2lo, w3hi, w3lo,
                     prot, fc2w, fcw, fcb, fc2b, P3, c3);
  hipLaunchKernelGGL(attn_a_kernel, dim3(BS), dim3(128), 0, stream, x, xsum);
  hipLaunchKernelGGL(attn_b_kernel, dim3(BS / MB), dim3(256), 0, stream,
                     xsum, wk, wq, vbuf);
  hipLaunchKernelGGL(attn_c_kernel, dim3(BS), dim3(192), 0, stream,
                     x, vbuf, gum, sec_idx);
  hipLaunchKernelGGL(conv_kernel, dim3(NSAMPLE), dim3(256), 0, stream,
                     x, sec_idx, w1, b1, bn1g, bn1b, w2hi, w2lo, b2, bn2g, bn2b,
                     w3hi, w3lo, b3, bn3g, bn3b, P3, c3, proto_idx);
  hipLaunchKernelGGL(seq_kernel, dim3(BB), dim3(512), 0, stream,
                     proto_idx, prot, inw, inb, outw, outb,
                     ln1g, ln1b, ln2g, ln2b, ff1w, ff1b, ff2w, ff2b,
                     clfw, clfb, out);
}